// Round 12
// baseline (526.286 us; speedup 1.0000x reference)
//
#include <hip/hip_runtime.h>
#include <hip/hip_fp16.h>

#define NUM_USERS 50000
#define NUM_ITEMS 100000
#define N_NODES   150000
#define EMBED     64
#define BATCH     4096
#define NNZ       2400000
#define NB        586     // ceil(N_NODES/256) for scan kernels
#define CBITS     10      // 1024 rows per coarse bucket
#define NCOARSE   147     // ceil(N_NODES/1024)
#define CAP       20480   // per-bucket tmp capacity
#define TILE      4096    // edges per partA block
#define NTILES    9375    // N_NODES/16 (exact)

typedef _Float16 half8 __attribute__((ext_vector_type(8)));
typedef float    f32x4 __attribute__((ext_vector_type(4)));

__device__ __forceinline__ float bf2f(unsigned short u) {
    union { unsigned int u32; float f; } v; v.u32 = ((unsigned int)u) << 16; return v.f;
}
__device__ __forceinline__ float getf(const void* p, int i, int fbf) {
    if (fbf) return bf2f(((const unsigned short*)p)[i]);
    return ((const float*)p)[i];
}
__device__ __forceinline__ int geti(const void* p, int i, int i64) {
    if (i64) return (int)(((const long long*)p)[i]);
    return ((const int*)p)[i];
}
__device__ __forceinline__ int clampi(int v, int lo, int hi) {
    return v < lo ? lo : (v > hi ? hi : v);
}
__device__ __forceinline__ float h2f(unsigned short u) {
    return __half2float(__ushort_as_half(u));
}
__device__ __forceinline__ unsigned short f2h(float f) {
    return __half_as_ushort(__float2half(f));
}

// -------- dtype probes --------
__global__ void k_flags_r23(const unsigned short* __restrict__ ev,
                            const void* __restrict__ er, int* __restrict__ fl) {
    if (threadIdx.x == 0 && blockIdx.x == 0) {
        int good = 0;
        for (int i = 0; i < 64; ++i) {
            float f = bf2f(ev[i]);
            if (f >= 0.0f && f <= 0.011f) good++;
        }
        fl[0] = (good >= 60) ? 1 : 0;
        int ok = 0;
        for (int i = 0; i < 64; ++i) {
            long long v = ((const long long*)er)[i];
            if (v >= 0 && v < (long long)N_NODES) ok++;
        }
        fl[1] = (ok >= 60) ? 1 : 0;
    }
}

// -------- MFMA layout probe (verified r22): sets fl[2] --------
__global__ void k_probe_r23(int* __restrict__ fl) {
    __shared__ unsigned short A[16 * 32];
    __shared__ unsigned short B[32 * 16];
    const int lane = threadIdx.x;
    for (int i = lane; i < 512; i += 64) {
        int r = i >> 5, k = i & 31;
        A[i] = f2h(((r * 7 + k * 3) % 23) * 0.04f - 0.4f);
    }
    for (int i = lane; i < 512; i += 64) {
        int k = i >> 4, n = i & 15;
        B[i] = f2h(((k * 11 + n * 5) % 19) * 0.05f - 0.45f);
    }
    __syncthreads();
    union { unsigned short u[8]; half8 h; } ua, ub;
    const int rA = lane & 15;
    const int g  = lane >> 4;
    #pragma unroll
    for (int e = 0; e < 8; ++e) {
        ua.u[e] = A[rA * 32 + g * 8 + e];
        ub.u[e] = B[(g * 8 + e) * 16 + rA];
    }
    f32x4 acc = {0.f, 0.f, 0.f, 0.f};
    acc = __builtin_amdgcn_mfma_f32_16x16x32_f16(ua.h, ub.h, acc, 0, 0, 0);
    bool ok = true;
    #pragma unroll
    for (int reg = 0; reg < 4; ++reg) {
        int row = g * 4 + reg;
        int col = lane & 15;
        float ref = 0.0f;
        for (int k = 0; k < 32; ++k)
            ref += h2f(A[row * 32 + k]) * h2f(B[k * 16 + col]);
        if (fabsf(acc[reg] - ref) > 0.02f * fmaxf(1.0f, fabsf(ref))) ok = false;
    }
    unsigned long long m = __ballot(ok);
    if (lane == 0) fl[2] = (m == ~0ull) ? 1 : 0;
}

// -------- E0 = concat(embed_user, embed_item) -> fp16 --------
__global__ void k_init_r23(const void* __restrict__ eu, const void* __restrict__ ei,
                           const int* __restrict__ fl, unsigned short* __restrict__ Eh) {
    int fbf = fl[0];
    int i = blockIdx.x * 256 + threadIdx.x;
    if (i < N_NODES * EMBED) {
        int r = i >> 6;
        float v;
        if (r < NUM_USERS) v = getf(eu, i, fbf);
        else               v = getf(ei, i - NUM_USERS * EMBED, fbf);
        Eh[i] = f2h(v);
    }
}

// ============ phase A: block-local counting sort into 147 coarse buckets ============
__global__ __launch_bounds__(256) void k_partA_r23(const void* __restrict__ ev,
                                                   const void* __restrict__ er,
                                                   const void* __restrict__ ec,
                                                   const int* __restrict__ fl,
                                                   int* __restrict__ ccur,
                                                   int2* __restrict__ tmp) {
    __shared__ int2 stage[TILE];
    __shared__ int  hist[NCOARSE];
    __shared__ int  base[NCOARSE];
    const int t   = threadIdx.x;
    const int i64 = fl[1], fbf = fl[0];
    for (int i = t; i < NCOARSE; i += 256) hist[i] = 0;
    __syncthreads();

    int  bx[16], ps[16];
    int2 pk[16];
    const int t0 = blockIdx.x * TILE;
    #pragma unroll
    for (int k = 0; k < 16; ++k) {
        int e = t0 + k * 256 + t;
        bx[k] = -1;
        if (e < NNZ) {
            int r = clampi(geti(er, e, i64), 0, N_NODES - 1);
            int c = clampi(geti(ec, e, i64), 0, N_NODES - 1);
            float v = getf(ev, e, fbf);
            int b = r >> CBITS;
            bx[k] = b;
            pk[k] = make_int2(((r & 1023) << 18) | c, __float_as_int(v));
            ps[k] = atomicAdd(&hist[b], 1);
        }
    }
    __syncthreads();
    if (t == 0) {
        int run = 0;
        for (int i = 0; i < NCOARSE; ++i) { base[i] = run; run += hist[i]; }
    }
    __syncthreads();
    #pragma unroll
    for (int k = 0; k < 16; ++k)
        if (bx[k] >= 0) stage[base[bx[k]] + ps[k]] = pk[k];
    __syncthreads();

    for (int b = t; b < NCOARSE; b += 256) {
        int n = hist[b];
        if (n == 0) continue;
        int g = atomicAdd(&ccur[b], n);
        int2* dst = tmp + (size_t)b * CAP;
        int s0 = base[b];
        for (int i = 0; i < n && (g + i) < CAP; ++i) dst[g + i] = stage[s0 + i];
    }
}

// ============ phase B1: per-bucket row histogram -> cnt[] ============
__global__ __launch_bounds__(256) void k_histB1_r23(const int* __restrict__ ccur,
                                                    const int2* __restrict__ tmp,
                                                    int* __restrict__ cnt) {
    __shared__ int h[1024];
    const int b = blockIdx.x;
    const int t = threadIdx.x;
    const int base_row = b << CBITS;
    int nrow = N_NODES - base_row; if (nrow > 1024) nrow = 1024;
    for (int i = t; i < 1024; i += 256) h[i] = 0;
    __syncthreads();
    int n = ccur[b]; if (n > CAP) n = CAP;
    const int2* src = tmp + (size_t)b * CAP;
    for (int p = t; p < n; p += 256) {
        int rl = src[p].x >> 18;
        atomicAdd(&h[rl], 1);
    }
    __syncthreads();
    for (int i = t; i < nrow; i += 256) cnt[base_row + i] = h[i];
}

// ============ scan (verified) ============
__global__ __launch_bounds__(256) void k_scanA_r23(const int* __restrict__ cnt,
                                                   int* __restrict__ bsum) {
    int i = blockIdx.x * 256 + threadIdx.x;
    int v = (i < N_NODES) ? cnt[i] : 0;
    #pragma unroll
    for (int d = 1; d < 64; d <<= 1) v += __shfl_xor(v, d, 64);
    __shared__ int sh[4];
    if ((threadIdx.x & 63) == 0) sh[threadIdx.x >> 6] = v;
    __syncthreads();
    if (threadIdx.x == 0) bsum[blockIdx.x] = sh[0] + sh[1] + sh[2] + sh[3];
}

__global__ __launch_bounds__(1024) void k_scanB_r23(int* __restrict__ bsum) {
    __shared__ int sh[1024];
    int t = threadIdx.x;
    if (t < NB) sh[t] = bsum[t];
    __syncthreads();
    if (t == 0) {
        int run = 0;
        for (int i = 0; i < NB; ++i) { int x = sh[i]; sh[i] = run; run += x; }
    }
    __syncthreads();
    if (t < NB) bsum[t] = sh[t];
}

__global__ __launch_bounds__(256) void k_scanC_r23(const int* __restrict__ cnt,
                                                   const int* __restrict__ bsum,
                                                   int* __restrict__ rowptr) {
    __shared__ int sh[256];
    int i = blockIdx.x * 256 + threadIdx.x;
    int t = threadIdx.x;
    sh[t] = (i < N_NODES) ? cnt[i] : 0;
    __syncthreads();
    if (t == 0) {
        int run = bsum[blockIdx.x];
        for (int k = 0; k < 256; ++k) { int x = sh[k]; sh[k] = run; run += x; }
    }
    __syncthreads();
    if (i < N_NODES) rowptr[i] = sh[t];
    if (i == 0) rowptr[N_NODES] = NNZ;
}

// ============ phase B2: place bucket windows into exact CSR slots ============
__global__ __launch_bounds__(256) void k_place_r23(const int* __restrict__ ccur,
                                                   const int2* __restrict__ tmp,
                                                   const int* __restrict__ rowptr,
                                                   int2* __restrict__ colcv) {
    __shared__ int rp[1025];
    __shared__ int cur[1024];
    const int b = blockIdx.x;
    const int t = threadIdx.x;
    const int base_row = b << CBITS;
    int nrow = N_NODES - base_row; if (nrow > 1024) nrow = 1024;
    for (int i = t; i <= nrow; i += 256) rp[i] = rowptr[base_row + i];
    for (int i = t; i < 1024; i += 256) cur[i] = 0;
    __syncthreads();
    int n = ccur[b]; if (n > CAP) n = CAP;
    const int2* src = tmp + (size_t)b * CAP;
    for (int p = t; p < n; p += 256) {
        int2 cv = src[p];
        int rl = cv.x >> 18;
        int c  = cv.x & 0x3FFFF;
        int dst = rp[rl] + atomicAdd(&cur[rl], 1);
        colcv[dst] = make_int2(c, cv.y);
    }
}

// ============ FUSED: per 16-row tile, gather -> LDS LE tile -> MFMA mlp -> Eout ======
// mfok==0: gather-only into LEh (fallback; k_mlpfb finishes the layer).
// Gather body verified r17..r22; MFMA+norm epilogue verified r22.
__global__ __launch_bounds__(256) void k_fuse_r23(const int* __restrict__ rowptr,
                                                  const int2* __restrict__ colcv,
                                                  const unsigned short* __restrict__ Ein,
                                                  unsigned short* __restrict__ Eout,
                                                  unsigned short* __restrict__ LEh,
                                                  const void* __restrict__ W1,
                                                  const void* __restrict__ B1,
                                                  const void* __restrict__ W2,
                                                  const void* __restrict__ B2,
                                                  const int* __restrict__ fl, int layer) {
    __shared__ unsigned short W12s[64 * 72];     // fp16 W1+W2, padded stride 72
    __shared__ unsigned short W1s [64 * 72];     // fp16 W1
    __shared__ unsigned short LEt[4][16 * 72];   // per-wave LE tile (fp16)
    const int fbf  = fl[0];
    const int mfok = fl[2];
    const int wofs = layer * EMBED * EMBED;
    const int bofs = layer * EMBED;
    const int t    = threadIdx.x;
    const int lane = t & 63;
    const int w    = t >> 6;
    const int g    = lane >> 4;    // quad group 0..3
    const int q    = lane & 15;    // 16-slot index (gather: col quarter; mfma: col)

    if (mfok) {
        for (int i = t; i < 4096; i += 256) {
            int idx = (i >> 6) * 72 + (i & 63);
            float w1 = getf(W1, wofs + i, fbf);
            float w2 = getf(W2, wofs + i, fbf);
            W1s [idx] = f2h(w1);
            W12s[idx] = f2h(w1 + w2);
        }
        __syncthreads();
    }

    float bias[4];
    #pragma unroll
    for (int nt = 0; nt < 4; ++nt)
        bias[nt] = getf(B1, bofs + nt * 16 + q, fbf) + getf(B2, bofs + nt * 16 + q, fbf);

    const int gw = blockIdx.x * 4 + w;
    const int nw = gridDim.x * 4;

    for (int tile = gw; tile < NTILES; tile += nw) {
        const int r0 = tile * 16;

        // ---- phase 1: gather 16 rows into the wave's LDS LE tile ----
        for (int rr = 0; rr < 16; ++rr) {
            const int row = r0 + rr;
            const int s = rowptr[row];
            const int e = rowptr[row + 1];
            float a0 = 0.f, a1 = 0.f, a2 = 0.f, a3 = 0.f;
            for (int base = s; base < e; base += 64) {
                int idx = base + lane;
                int2 cv = make_int2(0, 0);
                if (idx < e) cv = colcv[idx];
                int m = e - base; if (m > 64) m = 64;
                for (int j = 0; j < m; j += 8) {
                    int i0 = j + g;
                    int i1 = j + 4 + g;
                    bool v0 = i0 < m;
                    bool v1 = i1 < m;
                    int   c0 = __shfl(cv.x, i0, 64);
                    float f0 = __int_as_float(__shfl(cv.y, i0, 64));
                    int   c1 = __shfl(cv.x, i1, 64);
                    float f1 = __int_as_float(__shfl(cv.y, i1, 64));
                    c0 = v0 ? c0 : 0;  f0 = v0 ? f0 : 0.0f;
                    c1 = v1 ? c1 : 0;  f1 = v1 ? f1 : 0.0f;
                    ushort4 p0 = *reinterpret_cast<const ushort4*>(&Ein[c0 * EMBED + 4 * q]);
                    ushort4 p1 = *reinterpret_cast<const ushort4*>(&Ein[c1 * EMBED + 4 * q]);
                    a0 = fmaf(f0, h2f(p0.x), a0);
                    a1 = fmaf(f0, h2f(p0.y), a1);
                    a2 = fmaf(f0, h2f(p0.z), a2);
                    a3 = fmaf(f0, h2f(p0.w), a3);
                    a0 = fmaf(f1, h2f(p1.x), a0);
                    a1 = fmaf(f1, h2f(p1.y), a1);
                    a2 = fmaf(f1, h2f(p1.z), a2);
                    a3 = fmaf(f1, h2f(p1.w), a3);
                }
            }
            #pragma unroll
            for (int d = 16; d < 64; d <<= 1) {
                a0 += __shfl_xor(a0, d, 64);
                a1 += __shfl_xor(a1, d, 64);
                a2 += __shfl_xor(a2, d, 64);
                a3 += __shfl_xor(a3, d, 64);
            }
            if (g == 0) {
                ushort4 o;
                o.x = f2h(a0); o.y = f2h(a1); o.z = f2h(a2); o.w = f2h(a3);
                if (mfok) {
                    *reinterpret_cast<ushort4*>(&LEt[w][rr * 72 + 4 * q]) = o;
                } else {
                    *reinterpret_cast<ushort4*>(&LEh[row * EMBED + 4 * q]) = o;
                }
            }
        }
        if (!mfok) continue;   // fallback: k_mlpfb finishes

        // ---- phase 2: MFMA mlp on the tile (A-LE from LDS, A-E from global) ----
        half8 aLE0 = *reinterpret_cast<const half8*>(&LEt[w][q * 72 + 0  + g * 8]);
        half8 aLE1 = *reinterpret_cast<const half8*>(&LEt[w][q * 72 + 32 + g * 8]);
        const unsigned short* erow = &Ein[(r0 + q) * EMBED];
        half8 aE0  = *reinterpret_cast<const half8*>(&erow[0  + g * 8]);
        half8 aE1  = *reinterpret_cast<const half8*>(&erow[32 + g * 8]);

        f32x4 acc0 = {bias[0], bias[0], bias[0], bias[0]};
        f32x4 acc1 = {bias[1], bias[1], bias[1], bias[1]};
        f32x4 acc2 = {bias[2], bias[2], bias[2], bias[2]};
        f32x4 acc3 = {bias[3], bias[3], bias[3], bias[3]};

        #pragma unroll
        for (int nt = 0; nt < 4; ++nt) {
            const int nrow = (nt * 16 + q) * 72;
            half8 b12_0 = *reinterpret_cast<const half8*>(&W12s[nrow + 0  + g * 8]);
            half8 b12_1 = *reinterpret_cast<const half8*>(&W12s[nrow + 32 + g * 8]);
            half8 b1_0  = *reinterpret_cast<const half8*>(&W1s [nrow + 0  + g * 8]);
            half8 b1_1  = *reinterpret_cast<const half8*>(&W1s [nrow + 32 + g * 8]);
            // note: B-frag of output-col group nt must multiply every A; accumulate
            // into acc<nt>. Select via if-chain kept branchless by unroll.
            f32x4 a = (nt == 0) ? acc0 : (nt == 1) ? acc1 : (nt == 2) ? acc2 : acc3;
            a = __builtin_amdgcn_mfma_f32_16x16x32_f16(aLE0, b12_0, a, 0, 0, 0);
            a = __builtin_amdgcn_mfma_f32_16x16x32_f16(aLE1, b12_1, a, 0, 0, 0);
            a = __builtin_amdgcn_mfma_f32_16x16x32_f16(aE0,  b1_0,  a, 0, 0, 0);
            a = __builtin_amdgcn_mfma_f32_16x16x32_f16(aE1,  b1_1,  a, 0, 0, 0);
            if (nt == 0) acc0 = a; else if (nt == 1) acc1 = a; else if (nt == 2) acc2 = a; else acc3 = a;
        }

        // leaky + row-norm epilogue (verified r22); D: col=q, row=g*4+rg
        f32x4 h0, h1, h2, h3;
        float p0 = 0.f, p1 = 0.f, p2 = 0.f, p3 = 0.f;
        #pragma unroll
        for (int rg = 0; rg < 4; ++rg) {
            float a = acc0[rg]; float hh = (a > 0.f) ? a : 0.2f * a; h0[rg] = hh;
            float s = hh * hh;
            a = acc1[rg]; hh = (a > 0.f) ? a : 0.2f * a; h1[rg] = hh; s += hh * hh;
            a = acc2[rg]; hh = (a > 0.f) ? a : 0.2f * a; h2[rg] = hh; s += hh * hh;
            a = acc3[rg]; hh = (a > 0.f) ? a : 0.2f * a; h3[rg] = hh; s += hh * hh;
            if (rg == 0) p0 = s; else if (rg == 1) p1 = s; else if (rg == 2) p2 = s; else p3 = s;
        }
        #pragma unroll
        for (int d = 1; d < 16; d <<= 1) {
            p0 += __shfl_xor(p0, d, 64);
            p1 += __shfl_xor(p1, d, 64);
            p2 += __shfl_xor(p2, d, 64);
            p3 += __shfl_xor(p3, d, 64);
        }
        float inv0 = 1.0f / fmaxf(sqrtf(p0), 1e-12f);
        float inv1 = 1.0f / fmaxf(sqrtf(p1), 1e-12f);
        float inv2 = 1.0f / fmaxf(sqrtf(p2), 1e-12f);
        float inv3 = 1.0f / fmaxf(sqrtf(p3), 1e-12f);

        #pragma unroll
        for (int rg = 0; rg < 4; ++rg) {
            float inv = (rg == 0) ? inv0 : (rg == 1) ? inv1 : (rg == 2) ? inv2 : inv3;
            unsigned short* orow = &Eout[(r0 + g * 4 + rg) * EMBED + q];
            orow[0]  = f2h(h0[rg] * inv);
            orow[16] = f2h(h1[rg] * inv);
            orow[32] = f2h(h2[rg] * inv);
            orow[48] = f2h(h3[rg] * inv);
        }
    }
}

// -------- fallback dense layer (VALU, verified r21): Ein,LEh -> Eout; no-op if mfok --------
__global__ __launch_bounds__(256) void k_mlpfb_r23(const unsigned short* __restrict__ Ein,
                                                   unsigned short* __restrict__ Eout,
                                                   const unsigned short* __restrict__ LEh,
                                                   const void* __restrict__ W1,
                                                   const void* __restrict__ B1,
                                                   const void* __restrict__ W2,
                                                   const void* __restrict__ B2,
                                                   const int* __restrict__ fl, int layer) {
    if (fl[2]) return;
    __shared__ float4 XA[4][16];
    __shared__ float4 XB[4][16];
    const int fbf  = fl[0];
    const int wofs = layer * EMBED * EMBED;
    const int bofs = layer * EMBED;
    const int lane = threadIdx.x & 63;
    const int w    = threadIdx.x >> 6;

    float w1r[64], w12r[64];
    if (fbf) {
        const unsigned short* p1 = (const unsigned short*)W1 + wofs + lane * 64;
        const unsigned short* p2 = (const unsigned short*)W2 + wofs + lane * 64;
        #pragma unroll
        for (int q = 0; q < 16; ++q) {
            ushort4 a = reinterpret_cast<const ushort4*>(p1)[q];
            ushort4 b = reinterpret_cast<const ushort4*>(p2)[q];
            float f0 = bf2f(a.x), f1 = bf2f(a.y), f2 = bf2f(a.z), f3 = bf2f(a.w);
            w1r[4*q+0] = f0; w1r[4*q+1] = f1; w1r[4*q+2] = f2; w1r[4*q+3] = f3;
            w12r[4*q+0] = f0 + bf2f(b.x); w12r[4*q+1] = f1 + bf2f(b.y);
            w12r[4*q+2] = f2 + bf2f(b.z); w12r[4*q+3] = f3 + bf2f(b.w);
        }
    } else {
        const float* p1 = (const float*)W1 + wofs + lane * 64;
        const float* p2 = (const float*)W2 + wofs + lane * 64;
        #pragma unroll
        for (int q = 0; q < 16; ++q) {
            float4 a = reinterpret_cast<const float4*>(p1)[q];
            float4 b = reinterpret_cast<const float4*>(p2)[q];
            w1r[4*q+0] = a.x; w1r[4*q+1] = a.y; w1r[4*q+2] = a.z; w1r[4*q+3] = a.w;
            w12r[4*q+0] = a.x + b.x; w12r[4*q+1] = a.y + b.y;
            w12r[4*q+2] = a.z + b.z; w12r[4*q+3] = a.w + b.w;
        }
    }
    const float bias = getf(B1, bofs + lane, fbf) + getf(B2, bofs + lane, fbf);

    const int gw = blockIdx.x * 4 + w;
    const int nw = gridDim.x * 4;
    for (int row = gw; row < N_NODES; row += nw) {
        float le = h2f(LEh[row * EMBED + lane]);
        float ee = h2f(Ein[row * EMBED + lane]);
        ((float*)&XA[w][0])[lane] = le;
        ((float*)&XB[w][0])[lane] = ee;
        float acc0 = bias, acc1 = 0.0f;
        #pragma unroll
        for (int q = 0; q < 16; ++q) {
            float4 a = XA[w][q];
            float4 b = XB[w][q];
            acc0 = fmaf(a.x, w12r[4*q+0], acc0);
            acc1 = fmaf(b.x, w1r [4*q+0], acc1);
            acc0 = fmaf(a.y, w12r[4*q+1], acc0);
            acc1 = fmaf(b.y, w1r [4*q+1], acc1);
            acc0 = fmaf(a.z, w12r[4*q+2], acc0);
            acc1 = fmaf(b.z, w1r [4*q+2], acc1);
            acc0 = fmaf(a.w, w12r[4*q+3], acc0);
            acc1 = fmaf(b.w, w1r [4*q+3], acc1);
        }
        float acc = acc0 + acc1;
        float h = (acc > 0.0f) ? acc : 0.2f * acc;
        float s = h * h;
        #pragma unroll
        for (int d = 1; d < 64; d <<= 1) s += __shfl_xor(s, d, 64);
        const float inv = 1.0f / fmaxf(sqrtf(s), 1e-12f);
        Eout[row * EMBED + lane] = f2h(h * inv);
    }
}

// -------- gather batch rows into FLOAT output --------
__global__ void k_pick_r23(const unsigned short* __restrict__ Eh, const void* __restrict__ bu,
                           const void* __restrict__ bp, const void* __restrict__ bn,
                           const int* __restrict__ fl,
                           float* __restrict__ out, int stage) {
    int i64 = fl[1];
    int i = blockIdx.x * 256 + threadIdx.x;
    if (i >= 3 * BATCH * EMBED) return;
    int c = i & 63;
    int row = i >> 6;
    int o = row >> 12;
    int b = row & 4095;
    int idx;
    if (o == 0)      idx = geti(bu, b, i64);
    else if (o == 1) idx = geti(bp, b, i64);
    else             idx = geti(bn, b, i64);
    int src;
    if (o == 0) src = clampi(idx, 0, NUM_USERS - 1);
    else        src = NUM_USERS + clampi(idx, 0, NUM_ITEMS - 1);
    int pos = o * (BATCH * 256) + b * 256 + stage * 64 + c;
    out[pos] = h2f(Eh[src * EMBED + c]);
}

// -------- launch --------
extern "C" void kernel_launch(void* const* d_in, const int* in_sizes, int n_in,
                              void* d_out, int out_size, void* d_ws, size_t ws_size,
                              hipStream_t stream) {
    const void* edge_val = d_in[0];
    const void* emb_u    = d_in[1];
    const void* emb_i    = d_in[2];
    const void* W1w      = d_in[3];
    const void* W1b      = d_in[4];
    const void* W2w      = d_in[5];
    const void* W2b      = d_in[6];
    const void* erow     = d_in[7];
    const void* ecol     = d_in[8];
    const void* bu       = d_in[9];
    const void* bp       = d_in[10];
    const void* bn       = d_in[11];

    const size_t EHB  = (size_t)N_NODES * EMBED * 2;            // 19.2 MB fp16
    const size_t RPB  = 600064;                                  // rowptr
    const size_t CNB  = 600064;                                  // cnt
    const size_t BSB  = 4096;                                    // block sums
    const size_t CCB  = 4096;                                    // coarse cursors
    const size_t CVB2 = (size_t)NNZ * sizeof(int2);              // 19.2 MB final colcv
    const size_t TMPB = (size_t)NCOARSE * CAP * sizeof(int2);    // 24.1 MB bucket tmp

    const size_t need = 256 + 2 * EHB + RPB + CNB + BSB + CCB + CVB2 + TMPB;  // ~83 MB
    if (ws_size < need) return;   // zero-output signature

    char* ws = (char*)d_ws;
    int*            fl     = (int*)ws;
    unsigned short* E0     = (unsigned short*)(ws + 256);
    unsigned short* E1     = (unsigned short*)(ws + 256 + EHB);
    int*            rowptr = (int*)(ws + 256 + 2 * EHB);
    int*            cnt    = (int*)(ws + 256 + 2 * EHB + RPB);
    int*            bsum   = (int*)(ws + 256 + 2 * EHB + RPB + CNB);
    int*            ccur   = (int*)(ws + 256 + 2 * EHB + RPB + CNB + BSB);
    int2*           colcv  = (int2*)(ws + 256 + 2 * EHB + RPB + CNB + BSB + CCB);
    int2*           tmpcv  = (int2*)(ws + 256 + 2 * EHB + RPB + CNB + BSB + CCB + CVB2);
    unsigned short* LEh    = (unsigned short*)tmpcv;   // fallback LE; tmp dead after place
    float*          out    = (float*)d_out;

    k_flags_r23<<<1, 64, 0, stream>>>((const unsigned short*)edge_val, erow, fl);
    k_probe_r23<<<1, 64, 0, stream>>>(fl);

    k_init_r23<<<(N_NODES * EMBED + 255) / 256, 256, 0, stream>>>(emb_u, emb_i, fl, E0);

    hipMemsetAsync(ccur, 0, CCB, stream);
    k_partA_r23<<<(NNZ + TILE - 1) / TILE, 256, 0, stream>>>(edge_val, erow, ecol, fl,
                                                             ccur, tmpcv);
    k_histB1_r23<<<NCOARSE, 256, 0, stream>>>(ccur, tmpcv, cnt);
    k_scanA_r23<<<NB, 256, 0, stream>>>(cnt, bsum);
    k_scanB_r23<<<1, 1024, 0, stream>>>(bsum);
    k_scanC_r23<<<NB, 256, 0, stream>>>(cnt, bsum, rowptr);
    k_place_r23<<<NCOARSE, 256, 0, stream>>>(ccur, tmpcv, rowptr, colcv);

    k_pick_r23<<<(3 * BATCH * EMBED + 255) / 256, 256, 0, stream>>>(E0, bu, bp, bn, fl, out, 0);

    unsigned short* Ecur = E0;
    unsigned short* Enxt = E1;
    for (int l = 0; l < 3; ++l) {
        k_fuse_r23<<<2048, 256, 0, stream>>>(rowptr, colcv, Ecur, Enxt, LEh,
                                             W1w, W1b, W2w, W2b, fl, l);
        k_mlpfb_r23<<<1280, 256, 0, stream>>>(Ecur, Enxt, LEh,
                                              W1w, W1b, W2w, W2b, fl, l);
        unsigned short* tmp = Ecur; Ecur = Enxt; Enxt = tmp;
        k_pick_r23<<<(3 * BATCH * EMBED + 255) / 256, 256, 0, stream>>>(Ecur, bu, bp, bn, fl, out, l + 1);
    }
}

// Round 13
// 477.849 us; speedup vs baseline: 1.1014x; 1.1014x over previous
//
#include <hip/hip_runtime.h>
#include <hip/hip_fp16.h>

#define NUM_USERS 50000
#define NUM_ITEMS 100000
#define N_NODES   150000
#define EMBED     64
#define BATCH     4096
#define NNZ       2400000
#define CBITS     10      // 1024 rows per coarse bucket
#define NCOARSE   147     // ceil(N_NODES/1024)
#define CAP       20480   // per-bucket tmp capacity
#define TILE      4096    // edges per partA block
#define NTILES    9375    // N_NODES/16 (exact)

typedef _Float16 half8 __attribute__((ext_vector_type(8)));
typedef float    f32x4 __attribute__((ext_vector_type(4)));

__device__ __forceinline__ float bf2f(unsigned short u) {
    union { unsigned int u32; float f; } v; v.u32 = ((unsigned int)u) << 16; return v.f;
}
__device__ __forceinline__ float getf(const void* p, int i, int fbf) {
    if (fbf) return bf2f(((const unsigned short*)p)[i]);
    return ((const float*)p)[i];
}
__device__ __forceinline__ int geti(const void* p, int i, int i64) {
    if (i64) return (int)(((const long long*)p)[i]);
    return ((const int*)p)[i];
}
__device__ __forceinline__ int clampi(int v, int lo, int hi) {
    return v < lo ? lo : (v > hi ? hi : v);
}
__device__ __forceinline__ float h2f(unsigned short u) {
    return __half2float(__ushort_as_half(u));
}
__device__ __forceinline__ unsigned short f2h(float f) {
    return __half_as_ushort(__float2half(f));
}

// -------- setup: dtype flags + MFMA layout probe + ccur zero (merged, 1 dispatch) ----
__global__ void k_setup_r24(const unsigned short* __restrict__ ev,
                            const void* __restrict__ er,
                            int* __restrict__ fl, int* __restrict__ ccur) {
    __shared__ unsigned short A[16 * 32];
    __shared__ unsigned short B[32 * 16];
    const int lane = threadIdx.x;

    // zero coarse-bucket cursors
    for (int i = lane; i < NCOARSE; i += 64) ccur[i] = 0;

    // dtype flags
    if (lane == 0) {
        int good = 0;
        for (int i = 0; i < 64; ++i) {
            float f = bf2f(ev[i]);
            if (f >= 0.0f && f <= 0.011f) good++;
        }
        fl[0] = (good >= 60) ? 1 : 0;
        int ok = 0;
        for (int i = 0; i < 64; ++i) {
            long long v = ((const long long*)er)[i];
            if (v >= 0 && v < (long long)N_NODES) ok++;
        }
        fl[1] = (ok >= 60) ? 1 : 0;
    }

    // MFMA layout probe (verified r22): asymmetric A,B vs scalar reference
    for (int i = lane; i < 512; i += 64) {
        int r = i >> 5, k = i & 31;
        A[i] = f2h(((r * 7 + k * 3) % 23) * 0.04f - 0.4f);
    }
    for (int i = lane; i < 512; i += 64) {
        int k = i >> 4, n = i & 15;
        B[i] = f2h(((k * 11 + n * 5) % 19) * 0.05f - 0.45f);
    }
    __syncthreads();
    union { unsigned short u[8]; half8 h; } ua, ub;
    const int rA = lane & 15;
    const int g  = lane >> 4;
    #pragma unroll
    for (int e = 0; e < 8; ++e) {
        ua.u[e] = A[rA * 32 + g * 8 + e];
        ub.u[e] = B[(g * 8 + e) * 16 + rA];
    }
    f32x4 acc = {0.f, 0.f, 0.f, 0.f};
    acc = __builtin_amdgcn_mfma_f32_16x16x32_f16(ua.h, ub.h, acc, 0, 0, 0);
    bool ok2 = true;
    #pragma unroll
    for (int reg = 0; reg < 4; ++reg) {
        int row = g * 4 + reg;
        int col = lane & 15;
        float ref = 0.0f;
        for (int k = 0; k < 32; ++k)
            ref += h2f(A[row * 32 + k]) * h2f(B[k * 16 + col]);
        if (fabsf(acc[reg] - ref) > 0.02f * fmaxf(1.0f, fabsf(ref))) ok2 = false;
    }
    unsigned long long m = __ballot(ok2);
    if (lane == 0) fl[2] = (m == ~0ull) ? 1 : 0;
}

// -------- E0 = concat(embed_user, embed_item) -> fp16 --------
__global__ void k_init_r24(const void* __restrict__ eu, const void* __restrict__ ei,
                           const int* __restrict__ fl, unsigned short* __restrict__ Eh) {
    int fbf = fl[0];
    int i = blockIdx.x * 256 + threadIdx.x;
    if (i < N_NODES * EMBED) {
        int r = i >> 6;
        float v;
        if (r < NUM_USERS) v = getf(eu, i, fbf);
        else               v = getf(ei, i - NUM_USERS * EMBED, fbf);
        Eh[i] = f2h(v);
    }
}

// ============ phase A: block-local counting sort into 147 coarse buckets (verified) ==
__global__ __launch_bounds__(256) void k_partA_r24(const void* __restrict__ ev,
                                                   const void* __restrict__ er,
                                                   const void* __restrict__ ec,
                                                   const int* __restrict__ fl,
                                                   int* __restrict__ ccur,
                                                   int2* __restrict__ tmp) {
    __shared__ int2 stage[TILE];
    __shared__ int  hist[NCOARSE];
    __shared__ int  base[NCOARSE];
    const int t   = threadIdx.x;
    const int i64 = fl[1], fbf = fl[0];
    for (int i = t; i < NCOARSE; i += 256) hist[i] = 0;
    __syncthreads();

    int  bx[16], ps[16];
    int2 pk[16];
    const int t0 = blockIdx.x * TILE;
    #pragma unroll
    for (int k = 0; k < 16; ++k) {
        int e = t0 + k * 256 + t;
        bx[k] = -1;
        if (e < NNZ) {
            int r = clampi(geti(er, e, i64), 0, N_NODES - 1);
            int c = clampi(geti(ec, e, i64), 0, N_NODES - 1);
            float v = getf(ev, e, fbf);
            int b = r >> CBITS;
            bx[k] = b;
            pk[k] = make_int2(((r & 1023) << 18) | c, __float_as_int(v));
            ps[k] = atomicAdd(&hist[b], 1);
        }
    }
    __syncthreads();
    if (t == 0) {
        int run = 0;
        for (int i = 0; i < NCOARSE; ++i) { base[i] = run; run += hist[i]; }
    }
    __syncthreads();
    #pragma unroll
    for (int k = 0; k < 16; ++k)
        if (bx[k] >= 0) stage[base[bx[k]] + ps[k]] = pk[k];
    __syncthreads();

    for (int b = t; b < NCOARSE; b += 256) {
        int n = hist[b];
        if (n == 0) continue;
        int g = atomicAdd(&ccur[b], n);
        int2* dst = tmp + (size_t)b * CAP;
        int s0 = base[b];
        for (int i = 0; i < n && (g + i) < CAP; ++i) dst[g + i] = stage[s0 + i];
    }
}

// ============ bucket-base scan: bbase[b] = excl scan of clamped bucket sizes ========
__global__ void k_bscan_r24(const int* __restrict__ ccur, int* __restrict__ bbase,
                            int* __restrict__ rowptr) {
    if (threadIdx.x == 0) {
        int run = 0;
        for (int b = 0; b < NCOARSE; ++b) {
            bbase[b] = run;
            int n = ccur[b]; if (n > CAP) n = CAP;
            run += n;
        }
        bbase[NCOARSE] = run;
        rowptr[N_NODES] = run;
    }
}

// ============ place2: hist + in-LDS prefix + rowptr slice + place (merged) ==========
__global__ __launch_bounds__(256) void k_place2_r24(const int* __restrict__ ccur,
                                                    const int* __restrict__ bbase,
                                                    const int2* __restrict__ tmp,
                                                    int2* __restrict__ colcv,
                                                    int* __restrict__ rowptr) {
    __shared__ int h[1024];
    __shared__ int rp[1025];
    __shared__ int part[256];
    const int b = blockIdx.x;
    const int t = threadIdx.x;
    const int base_row = b << CBITS;
    int nrow = N_NODES - base_row; if (nrow > 1024) nrow = 1024;
    int n = ccur[b]; if (n > CAP) n = CAP;
    const int2* src = tmp + (size_t)b * CAP;
    const int bb = bbase[b];

    for (int i = t; i < 1024; i += 256) h[i] = 0;
    __syncthreads();
    for (int p = t; p < n; p += 256) atomicAdd(&h[src[p].x >> 18], 1);
    __syncthreads();

    // hierarchical exclusive prefix over 1024 (scanC's verified serial-256 core)
    part[t] = h[4 * t] + h[4 * t + 1] + h[4 * t + 2] + h[4 * t + 3];
    __syncthreads();
    if (t == 0) {
        int run = bb;
        for (int i = 0; i < 256; ++i) { int x = part[i]; part[i] = run; run += x; }
    }
    __syncthreads();
    {
        int run = part[t];
        rp[4 * t] = run;               run += h[4 * t];
        rp[4 * t + 1] = run;           run += h[4 * t + 1];
        rp[4 * t + 2] = run;           run += h[4 * t + 2];
        rp[4 * t + 3] = run;
        if (t == 255) rp[1024] = run + h[1023];
    }
    __syncthreads();

    for (int i = t; i <= nrow; i += 256) rowptr[base_row + i] = rp[i];

    // reuse h as row cursors
    for (int i = t; i < 1024; i += 256) h[i] = 0;
    __syncthreads();
    for (int p = t; p < n; p += 256) {
        int2 cv = src[p];
        int rl = cv.x >> 18;
        int c  = cv.x & 0x3FFFF;
        int dst = rp[rl] + atomicAdd(&h[rl], 1);
        colcv[dst] = make_int2(c, cv.y);
    }
}

// ============ gather: LEh[r] = sum val*Eh[col] — fp16 rows, 4 edges/load (verified) ==
__global__ __launch_bounds__(256) void k_gath_r24(const int* __restrict__ rowptr,
                                                  const int2* __restrict__ colcv,
                                                  const unsigned short* __restrict__ Eh,
                                                  unsigned short* __restrict__ LEh) {
    int r = blockIdx.x * 4 + (threadIdx.x >> 6);
    if (r >= N_NODES) return;
    const int lane = threadIdx.x & 63;
    const int g = lane >> 4;
    const int q = lane & 15;
    const int s = rowptr[r];
    const int e = rowptr[r + 1];

    float a0 = 0.f, a1 = 0.f, a2 = 0.f, a3 = 0.f;

    for (int base = s; base < e; base += 64) {
        int idx = base + lane;
        int2 cv = make_int2(0, 0);
        if (idx < e) cv = colcv[idx];
        int m = e - base; if (m > 64) m = 64;

        for (int j = 0; j < m; j += 8) {
            int i0 = j + g;
            int i1 = j + 4 + g;
            bool v0 = i0 < m;
            bool v1 = i1 < m;
            int   c0 = __shfl(cv.x, i0, 64);
            float f0 = __int_as_float(__shfl(cv.y, i0, 64));
            int   c1 = __shfl(cv.x, i1, 64);
            float f1 = __int_as_float(__shfl(cv.y, i1, 64));
            c0 = v0 ? c0 : 0;  f0 = v0 ? f0 : 0.0f;
            c1 = v1 ? c1 : 0;  f1 = v1 ? f1 : 0.0f;
            ushort4 p0 = *reinterpret_cast<const ushort4*>(&Eh[c0 * EMBED + 4 * q]);
            ushort4 p1 = *reinterpret_cast<const ushort4*>(&Eh[c1 * EMBED + 4 * q]);
            a0 = fmaf(f0, h2f(p0.x), a0);
            a1 = fmaf(f0, h2f(p0.y), a1);
            a2 = fmaf(f0, h2f(p0.z), a2);
            a3 = fmaf(f0, h2f(p0.w), a3);
            a0 = fmaf(f1, h2f(p1.x), a0);
            a1 = fmaf(f1, h2f(p1.y), a1);
            a2 = fmaf(f1, h2f(p1.z), a2);
            a3 = fmaf(f1, h2f(p1.w), a3);
        }
    }

    #pragma unroll
    for (int d = 16; d < 64; d <<= 1) {
        a0 += __shfl_xor(a0, d, 64);
        a1 += __shfl_xor(a1, d, 64);
        a2 += __shfl_xor(a2, d, 64);
        a3 += __shfl_xor(a3, d, 64);
    }
    if (g == 0) {
        ushort4 o;
        o.x = f2h(a0); o.y = f2h(a1); o.z = f2h(a2); o.w = f2h(a3);
        *reinterpret_cast<ushort4*>(&LEh[r * EMBED + 4 * q]) = o;
    }
}

// ============ dense layer: MFMA (probe-gated) + verified VALU fallback (r22) ========
__global__ __launch_bounds__(256) void k_mlp_r24(unsigned short* __restrict__ Eh,
                                                 const unsigned short* __restrict__ LEh,
                                                 const void* __restrict__ W1,
                                                 const void* __restrict__ B1,
                                                 const void* __restrict__ W2,
                                                 const void* __restrict__ B2,
                                                 const int* __restrict__ fl, int layer) {
    __shared__ unsigned short W12s[64 * 72];
    __shared__ unsigned short W1s [64 * 72];
    __shared__ float4 XA[4][16];
    __shared__ float4 XB[4][16];
    const int fbf  = fl[0];
    const int mfok = fl[2];
    const int wofs = layer * EMBED * EMBED;
    const int bofs = layer * EMBED;
    const int t    = threadIdx.x;
    const int lane = t & 63;
    const int w    = t >> 6;

    if (mfok) {
        for (int i = t; i < 4096; i += 256) {
            int n = i >> 6, k = i & 63;
            float w1 = getf(W1, wofs + i, fbf);
            float w2 = getf(W2, wofs + i, fbf);
            W1s [n * 72 + k] = f2h(w1);
            W12s[n * 72 + k] = f2h(w1 + w2);
        }
        __syncthreads();

        const int cl = lane & 15;
        const int g  = lane >> 4;

        float bias[4];
        #pragma unroll
        for (int nt = 0; nt < 4; ++nt)
            bias[nt] = getf(B1, bofs + nt * 16 + cl, fbf) + getf(B2, bofs + nt * 16 + cl, fbf);

        half8 bw12_0[4], bw12_1[4], bw1_0[4], bw1_1[4];
        #pragma unroll
        for (int nt = 0; nt < 4; ++nt) {
            const int nrow = (nt * 16 + cl) * 72;
            bw12_0[nt] = *reinterpret_cast<const half8*>(&W12s[nrow + 0  + g * 8]);
            bw12_1[nt] = *reinterpret_cast<const half8*>(&W12s[nrow + 32 + g * 8]);
            bw1_0 [nt] = *reinterpret_cast<const half8*>(&W1s [nrow + 0  + g * 8]);
            bw1_1 [nt] = *reinterpret_cast<const half8*>(&W1s [nrow + 32 + g * 8]);
        }

        const int gw = blockIdx.x * 4 + w;
        const int nw = gridDim.x * 4;

        for (int tile = gw; tile < NTILES; tile += nw) {
            const int r0 = tile * 16;
            const unsigned short* lerow = &LEh[(r0 + cl) * EMBED];
            const unsigned short* erow  = &Eh [(r0 + cl) * EMBED];
            half8 aLE0 = *reinterpret_cast<const half8*>(&lerow[0  + g * 8]);
            half8 aLE1 = *reinterpret_cast<const half8*>(&lerow[32 + g * 8]);
            half8 aE0  = *reinterpret_cast<const half8*>(&erow [0  + g * 8]);
            half8 aE1  = *reinterpret_cast<const half8*>(&erow [32 + g * 8]);

            f32x4 acc0 = {bias[0], bias[0], bias[0], bias[0]};
            f32x4 acc1 = {bias[1], bias[1], bias[1], bias[1]};
            f32x4 acc2 = {bias[2], bias[2], bias[2], bias[2]};
            f32x4 acc3 = {bias[3], bias[3], bias[3], bias[3]};

            acc0 = __builtin_amdgcn_mfma_f32_16x16x32_f16(aLE0, bw12_0[0], acc0, 0, 0, 0);
            acc1 = __builtin_amdgcn_mfma_f32_16x16x32_f16(aLE0, bw12_0[1], acc1, 0, 0, 0);
            acc2 = __builtin_amdgcn_mfma_f32_16x16x32_f16(aLE0, bw12_0[2], acc2, 0, 0, 0);
            acc3 = __builtin_amdgcn_mfma_f32_16x16x32_f16(aLE0, bw12_0[3], acc3, 0, 0, 0);
            acc0 = __builtin_amdgcn_mfma_f32_16x16x32_f16(aLE1, bw12_1[0], acc0, 0, 0, 0);
            acc1 = __builtin_amdgcn_mfma_f32_16x16x32_f16(aLE1, bw12_1[1], acc1, 0, 0, 0);
            acc2 = __builtin_amdgcn_mfma_f32_16x16x32_f16(aLE1, bw12_1[2], acc2, 0, 0, 0);
            acc3 = __builtin_amdgcn_mfma_f32_16x16x32_f16(aLE1, bw12_1[3], acc3, 0, 0, 0);
            acc0 = __builtin_amdgcn_mfma_f32_16x16x32_f16(aE0,  bw1_0 [0], acc0, 0, 0, 0);
            acc1 = __builtin_amdgcn_mfma_f32_16x16x32_f16(aE0,  bw1_0 [1], acc1, 0, 0, 0);
            acc2 = __builtin_amdgcn_mfma_f32_16x16x32_f16(aE0,  bw1_0 [2], acc2, 0, 0, 0);
            acc3 = __builtin_amdgcn_mfma_f32_16x16x32_f16(aE0,  bw1_0 [3], acc3, 0, 0, 0);
            acc0 = __builtin_amdgcn_mfma_f32_16x16x32_f16(aE1,  bw1_1 [0], acc0, 0, 0, 0);
            acc1 = __builtin_amdgcn_mfma_f32_16x16x32_f16(aE1,  bw1_1 [1], acc1, 0, 0, 0);
            acc2 = __builtin_amdgcn_mfma_f32_16x16x32_f16(aE1,  bw1_1 [2], acc2, 0, 0, 0);
            acc3 = __builtin_amdgcn_mfma_f32_16x16x32_f16(aE1,  bw1_1 [3], acc3, 0, 0, 0);

            f32x4 h0, h1, h2, h3;
            float p0 = 0.f, p1 = 0.f, p2 = 0.f, p3 = 0.f;
            #pragma unroll
            for (int rg = 0; rg < 4; ++rg) {
                float a = acc0[rg]; float hh = (a > 0.f) ? a : 0.2f * a; h0[rg] = hh;
                float s = hh * hh;
                a = acc1[rg]; hh = (a > 0.f) ? a : 0.2f * a; h1[rg] = hh; s += hh * hh;
                a = acc2[rg]; hh = (a > 0.f) ? a : 0.2f * a; h2[rg] = hh; s += hh * hh;
                a = acc3[rg]; hh = (a > 0.f) ? a : 0.2f * a; h3[rg] = hh; s += hh * hh;
                if (rg == 0) p0 = s; else if (rg == 1) p1 = s; else if (rg == 2) p2 = s; else p3 = s;
            }
            #pragma unroll
            for (int d = 1; d < 16; d <<= 1) {
                p0 += __shfl_xor(p0, d, 64);
                p1 += __shfl_xor(p1, d, 64);
                p2 += __shfl_xor(p2, d, 64);
                p3 += __shfl_xor(p3, d, 64);
            }
            float inv0 = 1.0f / fmaxf(sqrtf(p0), 1e-12f);
            float inv1 = 1.0f / fmaxf(sqrtf(p1), 1e-12f);
            float inv2 = 1.0f / fmaxf(sqrtf(p2), 1e-12f);
            float inv3 = 1.0f / fmaxf(sqrtf(p3), 1e-12f);

            #pragma unroll
            for (int rg = 0; rg < 4; ++rg) {
                float inv = (rg == 0) ? inv0 : (rg == 1) ? inv1 : (rg == 2) ? inv2 : inv3;
                unsigned short* orow = &Eh[(r0 + g * 4 + rg) * EMBED + cl];
                orow[0]  = f2h(h0[rg] * inv);
                orow[16] = f2h(h1[rg] * inv);
                orow[32] = f2h(h2[rg] * inv);
                orow[48] = f2h(h3[rg] * inv);
            }
        }
        return;
    }

    // ---------- fallback: verified r21 VALU path ----------
    float w1r[64], w12r[64];
    if (fbf) {
        const unsigned short* p1 = (const unsigned short*)W1 + wofs + lane * 64;
        const unsigned short* p2 = (const unsigned short*)W2 + wofs + lane * 64;
        #pragma unroll
        for (int q = 0; q < 16; ++q) {
            ushort4 a = reinterpret_cast<const ushort4*>(p1)[q];
            ushort4 b = reinterpret_cast<const ushort4*>(p2)[q];
            float f0 = bf2f(a.x), f1 = bf2f(a.y), f2 = bf2f(a.z), f3 = bf2f(a.w);
            w1r[4*q+0] = f0; w1r[4*q+1] = f1; w1r[4*q+2] = f2; w1r[4*q+3] = f3;
            w12r[4*q+0] = f0 + bf2f(b.x); w12r[4*q+1] = f1 + bf2f(b.y);
            w12r[4*q+2] = f2 + bf2f(b.z); w12r[4*q+3] = f3 + bf2f(b.w);
        }
    } else {
        const float* p1 = (const float*)W1 + wofs + lane * 64;
        const float* p2 = (const float*)W2 + wofs + lane * 64;
        #pragma unroll
        for (int q = 0; q < 16; ++q) {
            float4 a = reinterpret_cast<const float4*>(p1)[q];
            float4 b = reinterpret_cast<const float4*>(p2)[q];
            w1r[4*q+0] = a.x; w1r[4*q+1] = a.y; w1r[4*q+2] = a.z; w1r[4*q+3] = a.w;
            w12r[4*q+0] = a.x + b.x; w12r[4*q+1] = a.y + b.y;
            w12r[4*q+2] = a.z + b.z; w12r[4*q+3] = a.w + b.w;
        }
    }
    const float bias = getf(B1, bofs + lane, fbf) + getf(B2, bofs + lane, fbf);

    const int gw = blockIdx.x * 4 + w;
    const int nw = gridDim.x * 4;

    int row = gw;
    float le = 0.0f, ee = 0.0f;
    if (row < N_NODES) {
        le = h2f(LEh[row * EMBED + lane]);
        ee = h2f(Eh[row * EMBED + lane]);
    }
    while (row < N_NODES) {
        const int nrow = row + nw;
        float nle = 0.0f, nee = 0.0f;
        if (nrow < N_NODES) {
            nle = h2f(LEh[nrow * EMBED + lane]);
            nee = h2f(Eh[nrow * EMBED + lane]);
        }

        ((float*)&XA[w][0])[lane] = le;
        ((float*)&XB[w][0])[lane] = ee;
        float acc0 = bias, acc1 = 0.0f;
        #pragma unroll
        for (int q = 0; q < 16; ++q) {
            float4 a = XA[w][q];
            float4 b = XB[w][q];
            acc0 = fmaf(a.x, w12r[4*q+0], acc0);
            acc1 = fmaf(b.x, w1r [4*q+0], acc1);
            acc0 = fmaf(a.y, w12r[4*q+1], acc0);
            acc1 = fmaf(b.y, w1r [4*q+1], acc1);
            acc0 = fmaf(a.z, w12r[4*q+2], acc0);
            acc1 = fmaf(b.z, w1r [4*q+2], acc1);
            acc0 = fmaf(a.w, w12r[4*q+3], acc0);
            acc1 = fmaf(b.w, w1r [4*q+3], acc1);
        }
        float acc = acc0 + acc1;
        float h = (acc > 0.0f) ? acc : 0.2f * acc;

        float s = h * h;
        #pragma unroll
        for (int d = 1; d < 64; d <<= 1) s += __shfl_xor(s, d, 64);
        const float inv = 1.0f / fmaxf(sqrtf(s), 1e-12f);

        Eh[row * EMBED + lane] = f2h(h * inv);

        row = nrow; le = nle; ee = nee;
    }
}

// -------- gather batch rows into FLOAT output --------
__global__ void k_pick_r24(const unsigned short* __restrict__ Eh, const void* __restrict__ bu,
                           const void* __restrict__ bp, const void* __restrict__ bn,
                           const int* __restrict__ fl,
                           float* __restrict__ out, int stage) {
    int i64 = fl[1];
    int i = blockIdx.x * 256 + threadIdx.x;
    if (i >= 3 * BATCH * EMBED) return;
    int c = i & 63;
    int row = i >> 6;
    int o = row >> 12;
    int b = row & 4095;
    int idx;
    if (o == 0)      idx = geti(bu, b, i64);
    else if (o == 1) idx = geti(bp, b, i64);
    else             idx = geti(bn, b, i64);
    int src;
    if (o == 0) src = clampi(idx, 0, NUM_USERS - 1);
    else        src = NUM_USERS + clampi(idx, 0, NUM_ITEMS - 1);
    int pos = o * (BATCH * 256) + b * 256 + stage * 64 + c;
    out[pos] = h2f(Eh[src * EMBED + c]);
}

// -------- launch --------
extern "C" void kernel_launch(void* const* d_in, const int* in_sizes, int n_in,
                              void* d_out, int out_size, void* d_ws, size_t ws_size,
                              hipStream_t stream) {
    const void* edge_val = d_in[0];
    const void* emb_u    = d_in[1];
    const void* emb_i    = d_in[2];
    const void* W1w      = d_in[3];
    const void* W1b      = d_in[4];
    const void* W2w      = d_in[5];
    const void* W2b      = d_in[6];
    const void* erow     = d_in[7];
    const void* ecol     = d_in[8];
    const void* bu       = d_in[9];
    const void* bp       = d_in[10];
    const void* bn       = d_in[11];

    const size_t EHB  = (size_t)N_NODES * EMBED * 2;            // 19.2 MB fp16
    const size_t RPB  = 600064;                                  // rowptr (150001 ints)
    const size_t CCB  = 4096;                                    // coarse cursors
    const size_t BBB  = 4096;                                    // bucket bases (148 ints)
    const size_t CVB2 = (size_t)NNZ * sizeof(int2);              // 19.2 MB final colcv
    const size_t TMPB = (size_t)NCOARSE * CAP * sizeof(int2);    // 24.1 MB bucket tmp

    const size_t need = 256 + 2 * EHB + RPB + CCB + BBB + CVB2 + TMPB;   // ~82 MB
    if (ws_size < need) return;   // zero-output signature

    char* ws = (char*)d_ws;
    int*            fl     = (int*)ws;
    unsigned short* Eh     = (unsigned short*)(ws + 256);
    unsigned short* LEh    = (unsigned short*)(ws + 256 + EHB);
    int*            rowptr = (int*)(ws + 256 + 2 * EHB);
    int*            ccur   = (int*)(ws + 256 + 2 * EHB + RPB);
    int*            bbase  = (int*)(ws + 256 + 2 * EHB + RPB + CCB);
    int2*           colcv  = (int2*)(ws + 256 + 2 * EHB + RPB + CCB + BBB);
    int2*           tmpcv  = (int2*)(ws + 256 + 2 * EHB + RPB + CCB + BBB + CVB2);
    float*          out    = (float*)d_out;

    k_setup_r24<<<1, 64, 0, stream>>>((const unsigned short*)edge_val, erow, fl, ccur);

    k_init_r24<<<(N_NODES * EMBED + 255) / 256, 256, 0, stream>>>(emb_u, emb_i, fl, Eh);

    k_partA_r24<<<(NNZ + TILE - 1) / TILE, 256, 0, stream>>>(edge_val, erow, ecol, fl,
                                                             ccur, tmpcv);
    k_bscan_r24<<<1, 64, 0, stream>>>(ccur, bbase, rowptr);
    k_place2_r24<<<NCOARSE, 256, 0, stream>>>(ccur, bbase, tmpcv, colcv, rowptr);

    k_pick_r24<<<(3 * BATCH * EMBED + 255) / 256, 256, 0, stream>>>(Eh, bu, bp, bn, fl, out, 0);

    for (int l = 0; l < 3; ++l) {
        k_gath_r24<<<(N_NODES + 3) / 4, 256, 0, stream>>>(rowptr, colcv, Eh, LEh);
        k_mlp_r24<<<768, 256, 0, stream>>>(Eh, LEh, W1w, W1b, W2w, W2b, fl, l);
        k_pick_r24<<<(3 * BATCH * EMBED + 255) / 256, 256, 0, stream>>>(Eh, bu, bp, bn, fl, out, l + 1);
    }
}

// Round 14
// 469.513 us; speedup vs baseline: 1.1209x; 1.0178x over previous
//
#include <hip/hip_runtime.h>
#include <hip/hip_fp16.h>

#define NUM_USERS 50000
#define NUM_ITEMS 100000
#define N_NODES   150000
#define EMBED     64
#define BATCH     4096
#define NNZ       2400000
#define CBITS     10      // 1024 rows per coarse bucket
#define NCOARSE   147     // ceil(N_NODES/1024)
#define CAP       20480   // per-bucket tmp capacity
#define TILE      4096    // edges per partA block
#define NTILES    9375    // N_NODES/16 (exact)

typedef _Float16 half8 __attribute__((ext_vector_type(8)));
typedef float    f32x4 __attribute__((ext_vector_type(4)));

__device__ __forceinline__ float bf2f(unsigned short u) {
    union { unsigned int u32; float f; } v; v.u32 = ((unsigned int)u) << 16; return v.f;
}
__device__ __forceinline__ float getf(const void* p, int i, int fbf) {
    if (fbf) return bf2f(((const unsigned short*)p)[i]);
    return ((const float*)p)[i];
}
__device__ __forceinline__ int geti(const void* p, int i, int i64) {
    if (i64) return (int)(((const long long*)p)[i]);
    return ((const int*)p)[i];
}
__device__ __forceinline__ int clampi(int v, int lo, int hi) {
    return v < lo ? lo : (v > hi ? hi : v);
}
__device__ __forceinline__ float h2f(unsigned short u) {
    return __half2float(__ushort_as_half(u));
}
__device__ __forceinline__ unsigned short f2h(float f) {
    return __half_as_ushort(__float2half(f));
}

// -------- setup: dtype flags + MFMA layout probe + ccur zero (merged) --------
__global__ void k_setup_r25(const unsigned short* __restrict__ ev,
                            const void* __restrict__ er,
                            int* __restrict__ fl, int* __restrict__ ccur) {
    __shared__ unsigned short A[16 * 32];
    __shared__ unsigned short B[32 * 16];
    const int lane = threadIdx.x;

    for (int i = lane; i < NCOARSE; i += 64) ccur[i] = 0;

    if (lane == 0) {
        int good = 0;
        for (int i = 0; i < 64; ++i) {
            float f = bf2f(ev[i]);
            if (f >= 0.0f && f <= 0.011f) good++;
        }
        fl[0] = (good >= 60) ? 1 : 0;
        int ok = 0;
        for (int i = 0; i < 64; ++i) {
            long long v = ((const long long*)er)[i];
            if (v >= 0 && v < (long long)N_NODES) ok++;
        }
        fl[1] = (ok >= 60) ? 1 : 0;
    }

    for (int i = lane; i < 512; i += 64) {
        int r = i >> 5, k = i & 31;
        A[i] = f2h(((r * 7 + k * 3) % 23) * 0.04f - 0.4f);
    }
    for (int i = lane; i < 512; i += 64) {
        int k = i >> 4, n = i & 15;
        B[i] = f2h(((k * 11 + n * 5) % 19) * 0.05f - 0.45f);
    }
    __syncthreads();
    union { unsigned short u[8]; half8 h; } ua, ub;
    const int rA = lane & 15;
    const int g  = lane >> 4;
    #pragma unroll
    for (int e = 0; e < 8; ++e) {
        ua.u[e] = A[rA * 32 + g * 8 + e];
        ub.u[e] = B[(g * 8 + e) * 16 + rA];
    }
    f32x4 acc = {0.f, 0.f, 0.f, 0.f};
    acc = __builtin_amdgcn_mfma_f32_16x16x32_f16(ua.h, ub.h, acc, 0, 0, 0);
    bool ok2 = true;
    #pragma unroll
    for (int reg = 0; reg < 4; ++reg) {
        int row = g * 4 + reg;
        int col = lane & 15;
        float ref = 0.0f;
        for (int k = 0; k < 32; ++k)
            ref += h2f(A[row * 32 + k]) * h2f(B[k * 16 + col]);
        if (fabsf(acc[reg] - ref) > 0.02f * fmaxf(1.0f, fabsf(ref))) ok2 = false;
    }
    unsigned long long m = __ballot(ok2);
    if (lane == 0) fl[2] = (m == ~0ull) ? 1 : 0;
}

// -------- E0 = concat(embed_user, embed_item) -> fp16 --------
__global__ void k_init_r25(const void* __restrict__ eu, const void* __restrict__ ei,
                           const int* __restrict__ fl, unsigned short* __restrict__ Eh) {
    int fbf = fl[0];
    int i = blockIdx.x * 256 + threadIdx.x;
    if (i < N_NODES * EMBED) {
        int r = i >> 6;
        float v;
        if (r < NUM_USERS) v = getf(eu, i, fbf);
        else               v = getf(ei, i - NUM_USERS * EMBED, fbf);
        Eh[i] = f2h(v);
    }
}

// ============ phase A: block-local counting sort; val packed as half2(v,v) ==========
__global__ __launch_bounds__(256) void k_partA_r25(const void* __restrict__ ev,
                                                   const void* __restrict__ er,
                                                   const void* __restrict__ ec,
                                                   const int* __restrict__ fl,
                                                   int* __restrict__ ccur,
                                                   int2* __restrict__ tmp) {
    __shared__ int2 stage[TILE];
    __shared__ int  hist[NCOARSE];
    __shared__ int  base[NCOARSE];
    const int t   = threadIdx.x;
    const int i64 = fl[1], fbf = fl[0];
    for (int i = t; i < NCOARSE; i += 256) hist[i] = 0;
    __syncthreads();

    int  bx[16], ps[16];
    int2 pk[16];
    const int t0 = blockIdx.x * TILE;
    #pragma unroll
    for (int k = 0; k < 16; ++k) {
        int e = t0 + k * 256 + t;
        bx[k] = -1;
        if (e < NNZ) {
            int r = clampi(geti(er, e, i64), 0, N_NODES - 1);
            int c = clampi(geti(ec, e, i64), 0, N_NODES - 1);
            float v = getf(ev, e, fbf);
            unsigned int vh = f2h(v);
            int b = r >> CBITS;
            bx[k] = b;
            pk[k] = make_int2(((r & 1023) << 18) | c, (int)(vh | (vh << 16)));
            ps[k] = atomicAdd(&hist[b], 1);
        }
    }
    __syncthreads();
    if (t == 0) {
        int run = 0;
        for (int i = 0; i < NCOARSE; ++i) { base[i] = run; run += hist[i]; }
    }
    __syncthreads();
    #pragma unroll
    for (int k = 0; k < 16; ++k)
        if (bx[k] >= 0) stage[base[bx[k]] + ps[k]] = pk[k];
    __syncthreads();

    for (int b = t; b < NCOARSE; b += 256) {
        int n = hist[b];
        if (n == 0) continue;
        int g = atomicAdd(&ccur[b], n);
        int2* dst = tmp + (size_t)b * CAP;
        int s0 = base[b];
        for (int i = 0; i < n && (g + i) < CAP; ++i) dst[g + i] = stage[s0 + i];
    }
}

// ============ bucket-base scan ============
__global__ void k_bscan_r25(const int* __restrict__ ccur, int* __restrict__ bbase,
                            int* __restrict__ rowptr) {
    if (threadIdx.x == 0) {
        int run = 0;
        for (int b = 0; b < NCOARSE; ++b) {
            bbase[b] = run;
            int n = ccur[b]; if (n > CAP) n = CAP;
            run += n;
        }
        bbase[NCOARSE] = run;
        rowptr[N_NODES] = run;
    }
}

// ============ place2: hist + in-LDS prefix + rowptr slice + place (verified r24) =====
__global__ __launch_bounds__(256) void k_place2_r25(const int* __restrict__ ccur,
                                                    const int* __restrict__ bbase,
                                                    const int2* __restrict__ tmp,
                                                    int2* __restrict__ colcv,
                                                    int* __restrict__ rowptr) {
    __shared__ int h[1024];
    __shared__ int rp[1025];
    __shared__ int part[256];
    const int b = blockIdx.x;
    const int t = threadIdx.x;
    const int base_row = b << CBITS;
    int nrow = N_NODES - base_row; if (nrow > 1024) nrow = 1024;
    int n = ccur[b]; if (n > CAP) n = CAP;
    const int2* src = tmp + (size_t)b * CAP;
    const int bb = bbase[b];

    for (int i = t; i < 1024; i += 256) h[i] = 0;
    __syncthreads();
    for (int p = t; p < n; p += 256) atomicAdd(&h[src[p].x >> 18], 1);
    __syncthreads();

    part[t] = h[4 * t] + h[4 * t + 1] + h[4 * t + 2] + h[4 * t + 3];
    __syncthreads();
    if (t == 0) {
        int run = bb;
        for (int i = 0; i < 256; ++i) { int x = part[i]; part[i] = run; run += x; }
    }
    __syncthreads();
    {
        int run = part[t];
        rp[4 * t] = run;               run += h[4 * t];
        rp[4 * t + 1] = run;           run += h[4 * t + 1];
        rp[4 * t + 2] = run;           run += h[4 * t + 2];
        rp[4 * t + 3] = run;
        if (t == 255) rp[1024] = run + h[1023];
    }
    __syncthreads();

    for (int i = t; i <= nrow; i += 256) rowptr[base_row + i] = rp[i];

    for (int i = t; i < 1024; i += 256) h[i] = 0;
    __syncthreads();
    for (int p = t; p < n; p += 256) {
        int2 cv = src[p];
        int rl = cv.x >> 18;
        int c  = cv.x & 0x3FFFF;
        int dst = rp[rl] + atomicAdd(&h[rl], 1);
        colcv[dst] = make_int2(c, cv.y);
    }
}

// ============ gather: 8 edges per load instruction, packed-fp16 accumulate ==========
// lane = 8*g + q :  g = edge slot (0..7), q = 16B row-chunk (halves 8q..8q+7)
// colcv.y holds half2(v,v) pre-packed at build time.
__global__ __launch_bounds__(256) void k_gath_r25(const int* __restrict__ rowptr,
                                                  const int2* __restrict__ colcv,
                                                  const unsigned short* __restrict__ Eh,
                                                  unsigned short* __restrict__ LEh) {
    int r = blockIdx.x * 4 + (threadIdx.x >> 6);
    if (r >= N_NODES) return;
    const int lane = threadIdx.x & 63;
    const int g = lane >> 3;
    const int q = lane & 7;
    const int s = rowptr[r];
    const int e = rowptr[r + 1];

    __half2 acc0 = __float2half2_rn(0.f);
    __half2 acc1 = acc0, acc2 = acc0, acc3 = acc0;

    for (int base = s; base < e; base += 64) {
        int idx = base + lane;
        int2 cv = make_int2(0, 0);
        if (idx < e) cv = colcv[idx];
        int m = e - base; if (m > 64) m = 64;

        for (int j = 0; j < m; j += 8) {
            int i0 = j + g;
            bool v0 = i0 < m;
            int c0 = __shfl(cv.x, i0, 64);
            int vb = __shfl(cv.y, i0, 64);
            c0 = v0 ? c0 : 0;
            vb = v0 ? vb : 0;
            __half2 vh = *reinterpret_cast<__half2*>(&vb);
            union { float4 f; __half2 h[4]; } u;
            u.f = *reinterpret_cast<const float4*>(&Eh[c0 * EMBED + q * 8]);
            acc0 = __hfma2(vh, u.h[0], acc0);
            acc1 = __hfma2(vh, u.h[1], acc1);
            acc2 = __hfma2(vh, u.h[2], acc2);
            acc3 = __hfma2(vh, u.h[3], acc3);
        }
    }

    // fold the 8 edge-slot partials: lanes {q, q+8, ..., q+56} hold the same chunk
    unsigned u0 = *reinterpret_cast<unsigned*>(&acc0);
    unsigned u1 = *reinterpret_cast<unsigned*>(&acc1);
    unsigned u2 = *reinterpret_cast<unsigned*>(&acc2);
    unsigned u3 = *reinterpret_cast<unsigned*>(&acc3);
    #pragma unroll
    for (int d = 8; d < 64; d <<= 1) {
        unsigned t0 = __shfl_xor(u0, d, 64);
        unsigned t1 = __shfl_xor(u1, d, 64);
        unsigned t2 = __shfl_xor(u2, d, 64);
        unsigned t3 = __shfl_xor(u3, d, 64);
        __half2 a0 = *reinterpret_cast<__half2*>(&u0), b0 = *reinterpret_cast<__half2*>(&t0);
        __half2 a1 = *reinterpret_cast<__half2*>(&u1), b1 = *reinterpret_cast<__half2*>(&t1);
        __half2 a2 = *reinterpret_cast<__half2*>(&u2), b2 = *reinterpret_cast<__half2*>(&t2);
        __half2 a3 = *reinterpret_cast<__half2*>(&u3), b3 = *reinterpret_cast<__half2*>(&t3);
        a0 = __hadd2(a0, b0); a1 = __hadd2(a1, b1);
        a2 = __hadd2(a2, b2); a3 = __hadd2(a3, b3);
        u0 = *reinterpret_cast<unsigned*>(&a0);
        u1 = *reinterpret_cast<unsigned*>(&a1);
        u2 = *reinterpret_cast<unsigned*>(&a2);
        u3 = *reinterpret_cast<unsigned*>(&a3);
    }
    if (g == 0) {
        uint4 o = make_uint4(u0, u1, u2, u3);
        *reinterpret_cast<uint4*>(&LEh[r * EMBED + q * 8]) = o;
    }
}

// ============ dense layer: MFMA (probe-gated) + verified VALU fallback (r22) ========
__global__ __launch_bounds__(256) void k_mlp_r25(unsigned short* __restrict__ Eh,
                                                 const unsigned short* __restrict__ LEh,
                                                 const void* __restrict__ W1,
                                                 const void* __restrict__ B1,
                                                 const void* __restrict__ W2,
                                                 const void* __restrict__ B2,
                                                 const int* __restrict__ fl, int layer) {
    __shared__ unsigned short W12s[64 * 72];
    __shared__ unsigned short W1s [64 * 72];
    __shared__ float4 XA[4][16];
    __shared__ float4 XB[4][16];
    const int fbf  = fl[0];
    const int mfok = fl[2];
    const int wofs = layer * EMBED * EMBED;
    const int bofs = layer * EMBED;
    const int t    = threadIdx.x;
    const int lane = t & 63;
    const int w    = t >> 6;

    if (mfok) {
        for (int i = t; i < 4096; i += 256) {
            int n = i >> 6, k = i & 63;
            float w1 = getf(W1, wofs + i, fbf);
            float w2 = getf(W2, wofs + i, fbf);
            W1s [n * 72 + k] = f2h(w1);
            W12s[n * 72 + k] = f2h(w1 + w2);
        }
        __syncthreads();

        const int cl = lane & 15;
        const int g  = lane >> 4;

        float bias[4];
        #pragma unroll
        for (int nt = 0; nt < 4; ++nt)
            bias[nt] = getf(B1, bofs + nt * 16 + cl, fbf) + getf(B2, bofs + nt * 16 + cl, fbf);

        half8 bw12_0[4], bw12_1[4], bw1_0[4], bw1_1[4];
        #pragma unroll
        for (int nt = 0; nt < 4; ++nt) {
            const int nrow = (nt * 16 + cl) * 72;
            bw12_0[nt] = *reinterpret_cast<const half8*>(&W12s[nrow + 0  + g * 8]);
            bw12_1[nt] = *reinterpret_cast<const half8*>(&W12s[nrow + 32 + g * 8]);
            bw1_0 [nt] = *reinterpret_cast<const half8*>(&W1s [nrow + 0  + g * 8]);
            bw1_1 [nt] = *reinterpret_cast<const half8*>(&W1s [nrow + 32 + g * 8]);
        }

        const int gw = blockIdx.x * 4 + w;
        const int nw = gridDim.x * 4;

        for (int tile = gw; tile < NTILES; tile += nw) {
            const int r0 = tile * 16;
            const unsigned short* lerow = &LEh[(r0 + cl) * EMBED];
            const unsigned short* erow  = &Eh [(r0 + cl) * EMBED];
            half8 aLE0 = *reinterpret_cast<const half8*>(&lerow[0  + g * 8]);
            half8 aLE1 = *reinterpret_cast<const half8*>(&lerow[32 + g * 8]);
            half8 aE0  = *reinterpret_cast<const half8*>(&erow [0  + g * 8]);
            half8 aE1  = *reinterpret_cast<const half8*>(&erow [32 + g * 8]);

            f32x4 acc0 = {bias[0], bias[0], bias[0], bias[0]};
            f32x4 acc1 = {bias[1], bias[1], bias[1], bias[1]};
            f32x4 acc2 = {bias[2], bias[2], bias[2], bias[2]};
            f32x4 acc3 = {bias[3], bias[3], bias[3], bias[3]};

            acc0 = __builtin_amdgcn_mfma_f32_16x16x32_f16(aLE0, bw12_0[0], acc0, 0, 0, 0);
            acc1 = __builtin_amdgcn_mfma_f32_16x16x32_f16(aLE0, bw12_0[1], acc1, 0, 0, 0);
            acc2 = __builtin_amdgcn_mfma_f32_16x16x32_f16(aLE0, bw12_0[2], acc2, 0, 0, 0);
            acc3 = __builtin_amdgcn_mfma_f32_16x16x32_f16(aLE0, bw12_0[3], acc3, 0, 0, 0);
            acc0 = __builtin_amdgcn_mfma_f32_16x16x32_f16(aLE1, bw12_1[0], acc0, 0, 0, 0);
            acc1 = __builtin_amdgcn_mfma_f32_16x16x32_f16(aLE1, bw12_1[1], acc1, 0, 0, 0);
            acc2 = __builtin_amdgcn_mfma_f32_16x16x32_f16(aLE1, bw12_1[2], acc2, 0, 0, 0);
            acc3 = __builtin_amdgcn_mfma_f32_16x16x32_f16(aLE1, bw12_1[3], acc3, 0, 0, 0);
            acc0 = __builtin_amdgcn_mfma_f32_16x16x32_f16(aE0,  bw1_0 [0], acc0, 0, 0, 0);
            acc1 = __builtin_amdgcn_mfma_f32_16x16x32_f16(aE0,  bw1_0 [1], acc1, 0, 0, 0);
            acc2 = __builtin_amdgcn_mfma_f32_16x16x32_f16(aE0,  bw1_0 [2], acc2, 0, 0, 0);
            acc3 = __builtin_amdgcn_mfma_f32_16x16x32_f16(aE0,  bw1_0 [3], acc3, 0, 0, 0);
            acc0 = __builtin_amdgcn_mfma_f32_16x16x32_f16(aE1,  bw1_1 [0], acc0, 0, 0, 0);
            acc1 = __builtin_amdgcn_mfma_f32_16x16x32_f16(aE1,  bw1_1 [1], acc1, 0, 0, 0);
            acc2 = __builtin_amdgcn_mfma_f32_16x16x32_f16(aE1,  bw1_1 [2], acc2, 0, 0, 0);
            acc3 = __builtin_amdgcn_mfma_f32_16x16x32_f16(aE1,  bw1_1 [3], acc3, 0, 0, 0);

            f32x4 h0, h1, h2, h3;
            float p0 = 0.f, p1 = 0.f, p2 = 0.f, p3 = 0.f;
            #pragma unroll
            for (int rg = 0; rg < 4; ++rg) {
                float a = acc0[rg]; float hh = (a > 0.f) ? a : 0.2f * a; h0[rg] = hh;
                float s = hh * hh;
                a = acc1[rg]; hh = (a > 0.f) ? a : 0.2f * a; h1[rg] = hh; s += hh * hh;
                a = acc2[rg]; hh = (a > 0.f) ? a : 0.2f * a; h2[rg] = hh; s += hh * hh;
                a = acc3[rg]; hh = (a > 0.f) ? a : 0.2f * a; h3[rg] = hh; s += hh * hh;
                if (rg == 0) p0 = s; else if (rg == 1) p1 = s; else if (rg == 2) p2 = s; else p3 = s;
            }
            #pragma unroll
            for (int d = 1; d < 16; d <<= 1) {
                p0 += __shfl_xor(p0, d, 64);
                p1 += __shfl_xor(p1, d, 64);
                p2 += __shfl_xor(p2, d, 64);
                p3 += __shfl_xor(p3, d, 64);
            }
            float inv0 = 1.0f / fmaxf(sqrtf(p0), 1e-12f);
            float inv1 = 1.0f / fmaxf(sqrtf(p1), 1e-12f);
            float inv2 = 1.0f / fmaxf(sqrtf(p2), 1e-12f);
            float inv3 = 1.0f / fmaxf(sqrtf(p3), 1e-12f);

            #pragma unroll
            for (int rg = 0; rg < 4; ++rg) {
                float inv = (rg == 0) ? inv0 : (rg == 1) ? inv1 : (rg == 2) ? inv2 : inv3;
                unsigned short* orow = &Eh[(r0 + g * 4 + rg) * EMBED + cl];
                orow[0]  = f2h(h0[rg] * inv);
                orow[16] = f2h(h1[rg] * inv);
                orow[32] = f2h(h2[rg] * inv);
                orow[48] = f2h(h3[rg] * inv);
            }
        }
        return;
    }

    // ---------- fallback: verified r21 VALU path ----------
    float w1r[64], w12r[64];
    if (fbf) {
        const unsigned short* p1 = (const unsigned short*)W1 + wofs + lane * 64;
        const unsigned short* p2 = (const unsigned short*)W2 + wofs + lane * 64;
        #pragma unroll
        for (int q = 0; q < 16; ++q) {
            ushort4 a = reinterpret_cast<const ushort4*>(p1)[q];
            ushort4 b = reinterpret_cast<const ushort4*>(p2)[q];
            float f0 = bf2f(a.x), f1 = bf2f(a.y), f2 = bf2f(a.z), f3 = bf2f(a.w);
            w1r[4*q+0] = f0; w1r[4*q+1] = f1; w1r[4*q+2] = f2; w1r[4*q+3] = f3;
            w12r[4*q+0] = f0 + bf2f(b.x); w12r[4*q+1] = f1 + bf2f(b.y);
            w12r[4*q+2] = f2 + bf2f(b.z); w12r[4*q+3] = f3 + bf2f(b.w);
        }
    } else {
        const float* p1 = (const float*)W1 + wofs + lane * 64;
        const float* p2 = (const float*)W2 + wofs + lane * 64;
        #pragma unroll
        for (int q = 0; q < 16; ++q) {
            float4 a = reinterpret_cast<const float4*>(p1)[q];
            float4 b = reinterpret_cast<const float4*>(p2)[q];
            w1r[4*q+0] = a.x; w1r[4*q+1] = a.y; w1r[4*q+2] = a.z; w1r[4*q+3] = a.w;
            w12r[4*q+0] = a.x + b.x; w12r[4*q+1] = a.y + b.y;
            w12r[4*q+2] = a.z + b.z; w12r[4*q+3] = a.w + b.w;
        }
    }
    const float bias = getf(B1, bofs + lane, fbf) + getf(B2, bofs + lane, fbf);

    const int gw = blockIdx.x * 4 + w;
    const int nw = gridDim.x * 4;

    int row = gw;
    float le = 0.0f, ee = 0.0f;
    if (row < N_NODES) {
        le = h2f(LEh[row * EMBED + lane]);
        ee = h2f(Eh[row * EMBED + lane]);
    }
    while (row < N_NODES) {
        const int nrow = row + nw;
        float nle = 0.0f, nee = 0.0f;
        if (nrow < N_NODES) {
            nle = h2f(LEh[nrow * EMBED + lane]);
            nee = h2f(Eh[nrow * EMBED + lane]);
        }

        ((float*)&XA[w][0])[lane] = le;
        ((float*)&XB[w][0])[lane] = ee;
        float acc0 = bias, acc1 = 0.0f;
        #pragma unroll
        for (int q = 0; q < 16; ++q) {
            float4 a = XA[w][q];
            float4 b = XB[w][q];
            acc0 = fmaf(a.x, w12r[4*q+0], acc0);
            acc1 = fmaf(b.x, w1r [4*q+0], acc1);
            acc0 = fmaf(a.y, w12r[4*q+1], acc0);
            acc1 = fmaf(b.y, w1r [4*q+1], acc1);
            acc0 = fmaf(a.z, w12r[4*q+2], acc0);
            acc1 = fmaf(b.z, w1r [4*q+2], acc1);
            acc0 = fmaf(a.w, w12r[4*q+3], acc0);
            acc1 = fmaf(b.w, w1r [4*q+3], acc1);
        }
        float acc = acc0 + acc1;
        float h = (acc > 0.0f) ? acc : 0.2f * acc;

        float s = h * h;
        #pragma unroll
        for (int d = 1; d < 64; d <<= 1) s += __shfl_xor(s, d, 64);
        const float inv = 1.0f / fmaxf(sqrtf(s), 1e-12f);

        Eh[row * EMBED + lane] = f2h(h * inv);

        row = nrow; le = nle; ee = nee;
    }
}

// -------- gather batch rows into FLOAT output --------
__global__ void k_pick_r25(const unsigned short* __restrict__ Eh, const void* __restrict__ bu,
                           const void* __restrict__ bp, const void* __restrict__ bn,
                           const int* __restrict__ fl,
                           float* __restrict__ out, int stage) {
    int i64 = fl[1];
    int i = blockIdx.x * 256 + threadIdx.x;
    if (i >= 3 * BATCH * EMBED) return;
    int c = i & 63;
    int row = i >> 6;
    int o = row >> 12;
    int b = row & 4095;
    int idx;
    if (o == 0)      idx = geti(bu, b, i64);
    else if (o == 1) idx = geti(bp, b, i64);
    else             idx = geti(bn, b, i64);
    int src;
    if (o == 0) src = clampi(idx, 0, NUM_USERS - 1);
    else        src = NUM_USERS + clampi(idx, 0, NUM_ITEMS - 1);
    int pos = o * (BATCH * 256) + b * 256 + stage * 64 + c;
    out[pos] = h2f(Eh[src * EMBED + c]);
}

// -------- launch --------
extern "C" void kernel_launch(void* const* d_in, const int* in_sizes, int n_in,
                              void* d_out, int out_size, void* d_ws, size_t ws_size,
                              hipStream_t stream) {
    const void* edge_val = d_in[0];
    const void* emb_u    = d_in[1];
    const void* emb_i    = d_in[2];
    const void* W1w      = d_in[3];
    const void* W1b      = d_in[4];
    const void* W2w      = d_in[5];
    const void* W2b      = d_in[6];
    const void* erow     = d_in[7];
    const void* ecol     = d_in[8];
    const void* bu       = d_in[9];
    const void* bp       = d_in[10];
    const void* bn       = d_in[11];

    const size_t EHB  = (size_t)N_NODES * EMBED * 2;            // 19.2 MB fp16
    const size_t RPB  = 600064;                                  // rowptr (150001 ints)
    const size_t CCB  = 4096;                                    // coarse cursors
    const size_t BBB  = 4096;                                    // bucket bases
    const size_t CVB2 = (size_t)NNZ * sizeof(int2);              // 19.2 MB final colcv
    const size_t TMPB = (size_t)NCOARSE * CAP * sizeof(int2);    // 24.1 MB bucket tmp

    const size_t need = 256 + 2 * EHB + RPB + CCB + BBB + CVB2 + TMPB;   // ~82 MB
    if (ws_size < need) return;   // zero-output signature

    char* ws = (char*)d_ws;
    int*            fl     = (int*)ws;
    unsigned short* Eh     = (unsigned short*)(ws + 256);
    unsigned short* LEh    = (unsigned short*)(ws + 256 + EHB);
    int*            rowptr = (int*)(ws + 256 + 2 * EHB);
    int*            ccur   = (int*)(ws + 256 + 2 * EHB + RPB);
    int*            bbase  = (int*)(ws + 256 + 2 * EHB + RPB + CCB);
    int2*           colcv  = (int2*)(ws + 256 + 2 * EHB + RPB + CCB + BBB);
    int2*           tmpcv  = (int2*)(ws + 256 + 2 * EHB + RPB + CCB + BBB + CVB2);
    float*          out    = (float*)d_out;

    k_setup_r25<<<1, 64, 0, stream>>>((const unsigned short*)edge_val, erow, fl, ccur);

    k_init_r25<<<(N_NODES * EMBED + 255) / 256, 256, 0, stream>>>(emb_u, emb_i, fl, Eh);

    k_partA_r25<<<(NNZ + TILE - 1) / TILE, 256, 0, stream>>>(edge_val, erow, ecol, fl,
                                                             ccur, tmpcv);
    k_bscan_r25<<<1, 64, 0, stream>>>(ccur, bbase, rowptr);
    k_place2_r25<<<NCOARSE, 256, 0, stream>>>(ccur, bbase, tmpcv, colcv, rowptr);

    k_pick_r25<<<(3 * BATCH * EMBED + 255) / 256, 256, 0, stream>>>(Eh, bu, bp, bn, fl, out, 0);

    for (int l = 0; l < 3; ++l) {
        k_gath_r25<<<(N_NODES + 3) / 4, 256, 0, stream>>>(rowptr, colcv, Eh, LEh);
        k_mlp_r25<<<768, 256, 0, stream>>>(Eh, LEh, W1w, W1b, W2w, W2b, fl, l);
        k_pick_r25<<<(3 * BATCH * EMBED + 255) / 256, 256, 0, stream>>>(Eh, bu, bp, bn, fl, out, l + 1);
    }
}

// Round 15
// 464.874 us; speedup vs baseline: 1.1321x; 1.0100x over previous
//
#include <hip/hip_runtime.h>
#include <hip/hip_fp16.h>

#define NUM_USERS 50000
#define NUM_ITEMS 100000
#define N_NODES   150000
#define EMBED     64
#define BATCH     4096
#define NNZ       2400000
#define CBITS     10      // 1024 rows per coarse bucket
#define NCOARSE   147     // ceil(N_NODES/1024)
#define CAP       20480   // per-bucket tmp capacity
#define TILE      4096    // edges per partA block
#define NTILES    9375    // N_NODES/16 (exact)
#define PICKB     768     // pick blocks: 3*4096*16 quads / 256

typedef _Float16 half8 __attribute__((ext_vector_type(8)));
typedef float    f32x4 __attribute__((ext_vector_type(4)));

__device__ __forceinline__ float bf2f(unsigned short u) {
    union { unsigned int u32; float f; } v; v.u32 = ((unsigned int)u) << 16; return v.f;
}
__device__ __forceinline__ float getf(const void* p, int i, int fbf) {
    if (fbf) return bf2f(((const unsigned short*)p)[i]);
    return ((const float*)p)[i];
}
__device__ __forceinline__ int geti(const void* p, int i, int i64) {
    if (i64) return (int)(((const long long*)p)[i]);
    return ((const int*)p)[i];
}
__device__ __forceinline__ int clampi(int v, int lo, int hi) {
    return v < lo ? lo : (v > hi ? hi : v);
}
__device__ __forceinline__ float h2f(unsigned short u) {
    return __half2float(__ushort_as_half(u));
}
__device__ __forceinline__ unsigned short f2h(float f) {
    return __half_as_ushort(__float2half(f));
}

// vectorized pick: one thread = 4 consecutive cols of one output row (from Eh)
__device__ __forceinline__ void pick4_eh(const unsigned short* __restrict__ Eh,
                                         const void* __restrict__ bu,
                                         const void* __restrict__ bp,
                                         const void* __restrict__ bn,
                                         int i64, float* __restrict__ out,
                                         int stage, int gid) {
    if (gid >= 3 * BATCH * 16) return;
    int c4  = gid & 15;
    int row = gid >> 4;
    int o   = row >> 12;
    int b   = row & 4095;
    int idx;
    if (o == 0)      idx = geti(bu, b, i64);
    else if (o == 1) idx = geti(bp, b, i64);
    else             idx = geti(bn, b, i64);
    int src;
    if (o == 0) src = clampi(idx, 0, NUM_USERS - 1);
    else        src = NUM_USERS + clampi(idx, 0, NUM_ITEMS - 1);
    ushort4 v = *reinterpret_cast<const ushort4*>(&Eh[src * EMBED + c4 * 4]);
    float4 f = make_float4(h2f(v.x), h2f(v.y), h2f(v.z), h2f(v.w));
    int pos = o * (BATCH * 256) + b * 256 + stage * 64 + c4 * 4;
    *reinterpret_cast<float4*>(&out[pos]) = f;
}

// -------- setup: dtype flags + MFMA layout probe + ccur zero (merged) --------
__global__ void k_setup_r26(const unsigned short* __restrict__ ev,
                            const void* __restrict__ er,
                            int* __restrict__ fl, int* __restrict__ ccur) {
    __shared__ unsigned short A[16 * 32];
    __shared__ unsigned short B[32 * 16];
    const int lane = threadIdx.x;

    for (int i = lane; i < NCOARSE; i += 64) ccur[i] = 0;

    if (lane == 0) {
        int good = 0;
        for (int i = 0; i < 64; ++i) {
            float f = bf2f(ev[i]);
            if (f >= 0.0f && f <= 0.011f) good++;
        }
        fl[0] = (good >= 60) ? 1 : 0;
        int ok = 0;
        for (int i = 0; i < 64; ++i) {
            long long v = ((const long long*)er)[i];
            if (v >= 0 && v < (long long)N_NODES) ok++;
        }
        fl[1] = (ok >= 60) ? 1 : 0;
    }

    for (int i = lane; i < 512; i += 64) {
        int r = i >> 5, k = i & 31;
        A[i] = f2h(((r * 7 + k * 3) % 23) * 0.04f - 0.4f);
    }
    for (int i = lane; i < 512; i += 64) {
        int k = i >> 4, n = i & 15;
        B[i] = f2h(((k * 11 + n * 5) % 19) * 0.05f - 0.45f);
    }
    __syncthreads();
    union { unsigned short u[8]; half8 h; } ua, ub;
    const int rA = lane & 15;
    const int g  = lane >> 4;
    #pragma unroll
    for (int e = 0; e < 8; ++e) {
        ua.u[e] = A[rA * 32 + g * 8 + e];
        ub.u[e] = B[(g * 8 + e) * 16 + rA];
    }
    f32x4 acc = {0.f, 0.f, 0.f, 0.f};
    acc = __builtin_amdgcn_mfma_f32_16x16x32_f16(ua.h, ub.h, acc, 0, 0, 0);
    bool ok2 = true;
    #pragma unroll
    for (int reg = 0; reg < 4; ++reg) {
        int row = g * 4 + reg;
        int col = lane & 15;
        float ref = 0.0f;
        for (int k = 0; k < 32; ++k)
            ref += h2f(A[row * 32 + k]) * h2f(B[k * 16 + col]);
        if (fabsf(acc[reg] - ref) > 0.02f * fmaxf(1.0f, fabsf(ref))) ok2 = false;
    }
    unsigned long long m = __ballot(ok2);
    if (lane == 0) fl[2] = (m == ~0ull) ? 1 : 0;
}

// -------- init (+ pick stage-0 from RAW inputs in prefix blocks) --------
__global__ void k_init_r26(const void* __restrict__ eu, const void* __restrict__ ei,
                           const int* __restrict__ fl, unsigned short* __restrict__ Eh,
                           const void* __restrict__ bu, const void* __restrict__ bp,
                           const void* __restrict__ bn, float* __restrict__ out) {
    const int fbf = fl[0];
    if (blockIdx.x < PICKB) {
        // pick stage 0 straight from raw embeddings (no Eh dependency)
        int gid = blockIdx.x * 256 + threadIdx.x;
        if (gid >= 3 * BATCH * 16) return;
        int i64 = fl[1];
        int c4  = gid & 15;
        int row = gid >> 4;
        int o   = row >> 12;
        int b   = row & 4095;
        int idx;
        if (o == 0)      idx = geti(bu, b, i64);
        else if (o == 1) idx = geti(bp, b, i64);
        else             idx = geti(bn, b, i64);
        float4 f;
        if (o == 0) {
            int src = clampi(idx, 0, NUM_USERS - 1);
            int base = src * EMBED + c4 * 4;
            f = make_float4(getf(eu, base, fbf), getf(eu, base + 1, fbf),
                            getf(eu, base + 2, fbf), getf(eu, base + 3, fbf));
        } else {
            int src = clampi(idx, 0, NUM_ITEMS - 1);
            int base = src * EMBED + c4 * 4;
            f = make_float4(getf(ei, base, fbf), getf(ei, base + 1, fbf),
                            getf(ei, base + 2, fbf), getf(ei, base + 3, fbf));
        }
        int pos = o * (BATCH * 256) + b * 256 + c4 * 4;   // stage 0
        *reinterpret_cast<float4*>(&out[pos]) = f;
        return;
    }
    int i = (blockIdx.x - PICKB) * 256 + threadIdx.x;
    if (i < N_NODES * EMBED) {
        int r = i >> 6;
        float v;
        if (r < NUM_USERS) v = getf(eu, i, fbf);
        else               v = getf(ei, i - NUM_USERS * EMBED, fbf);
        Eh[i] = f2h(v);
    }
}

// ============ phase A: block-local counting sort; val packed as half2(v,v) ==========
__global__ __launch_bounds__(256) void k_partA_r26(const void* __restrict__ ev,
                                                   const void* __restrict__ er,
                                                   const void* __restrict__ ec,
                                                   const int* __restrict__ fl,
                                                   int* __restrict__ ccur,
                                                   int2* __restrict__ tmp) {
    __shared__ int2 stage[TILE];
    __shared__ int  hist[NCOARSE];
    __shared__ int  base[NCOARSE];
    const int t   = threadIdx.x;
    const int i64 = fl[1], fbf = fl[0];
    for (int i = t; i < NCOARSE; i += 256) hist[i] = 0;
    __syncthreads();

    int  bx[16], ps[16];
    int2 pk[16];
    const int t0 = blockIdx.x * TILE;
    #pragma unroll
    for (int k = 0; k < 16; ++k) {
        int e = t0 + k * 256 + t;
        bx[k] = -1;
        if (e < NNZ) {
            int r = clampi(geti(er, e, i64), 0, N_NODES - 1);
            int c = clampi(geti(ec, e, i64), 0, N_NODES - 1);
            float v = getf(ev, e, fbf);
            unsigned int vh = f2h(v);
            int b = r >> CBITS;
            bx[k] = b;
            pk[k] = make_int2(((r & 1023) << 18) | c, (int)(vh | (vh << 16)));
            ps[k] = atomicAdd(&hist[b], 1);
        }
    }
    __syncthreads();
    if (t == 0) {
        int run = 0;
        for (int i = 0; i < NCOARSE; ++i) { base[i] = run; run += hist[i]; }
    }
    __syncthreads();
    #pragma unroll
    for (int k = 0; k < 16; ++k)
        if (bx[k] >= 0) stage[base[bx[k]] + ps[k]] = pk[k];
    __syncthreads();

    for (int b = t; b < NCOARSE; b += 256) {
        int n = hist[b];
        if (n == 0) continue;
        int g = atomicAdd(&ccur[b], n);
        int2* dst = tmp + (size_t)b * CAP;
        int s0 = base[b];
        for (int i = 0; i < n && (g + i) < CAP; ++i) dst[g + i] = stage[s0 + i];
    }
}

// ============ bucket-base scan ============
__global__ void k_bscan_r26(const int* __restrict__ ccur, int* __restrict__ bbase,
                            int* __restrict__ rowptr) {
    if (threadIdx.x == 0) {
        int run = 0;
        for (int b = 0; b < NCOARSE; ++b) {
            bbase[b] = run;
            int n = ccur[b]; if (n > CAP) n = CAP;
            run += n;
        }
        bbase[NCOARSE] = run;
        rowptr[N_NODES] = run;
    }
}

// ============ place2: hist + in-LDS prefix + rowptr slice + place (verified r24) =====
__global__ __launch_bounds__(256) void k_place2_r26(const int* __restrict__ ccur,
                                                    const int* __restrict__ bbase,
                                                    const int2* __restrict__ tmp,
                                                    int2* __restrict__ colcv,
                                                    int* __restrict__ rowptr) {
    __shared__ int h[1024];
    __shared__ int rp[1025];
    __shared__ int part[256];
    const int b = blockIdx.x;
    const int t = threadIdx.x;
    const int base_row = b << CBITS;
    int nrow = N_NODES - base_row; if (nrow > 1024) nrow = 1024;
    int n = ccur[b]; if (n > CAP) n = CAP;
    const int2* src = tmp + (size_t)b * CAP;
    const int bb = bbase[b];

    for (int i = t; i < 1024; i += 256) h[i] = 0;
    __syncthreads();
    for (int p = t; p < n; p += 256) atomicAdd(&h[src[p].x >> 18], 1);
    __syncthreads();

    part[t] = h[4 * t] + h[4 * t + 1] + h[4 * t + 2] + h[4 * t + 3];
    __syncthreads();
    if (t == 0) {
        int run = bb;
        for (int i = 0; i < 256; ++i) { int x = part[i]; part[i] = run; run += x; }
    }
    __syncthreads();
    {
        int run = part[t];
        rp[4 * t] = run;               run += h[4 * t];
        rp[4 * t + 1] = run;           run += h[4 * t + 1];
        rp[4 * t + 2] = run;           run += h[4 * t + 2];
        rp[4 * t + 3] = run;
        if (t == 255) rp[1024] = run + h[1023];
    }
    __syncthreads();

    for (int i = t; i <= nrow; i += 256) rowptr[base_row + i] = rp[i];

    for (int i = t; i < 1024; i += 256) h[i] = 0;
    __syncthreads();
    for (int p = t; p < n; p += 256) {
        int2 cv = src[p];
        int rl = cv.x >> 18;
        int c  = cv.x & 0x3FFFF;
        int dst = rp[rl] + atomicAdd(&h[rl], 1);
        colcv[dst] = make_int2(c, cv.y);
    }
}

// ============ gather (verified r25) + optional pick prefix blocks ==================
__global__ __launch_bounds__(256) void k_gath_r26(const int* __restrict__ rowptr,
                                                  const int2* __restrict__ colcv,
                                                  const unsigned short* __restrict__ Eh,
                                                  unsigned short* __restrict__ LEh,
                                                  const void* __restrict__ bu,
                                                  const void* __restrict__ bp,
                                                  const void* __restrict__ bn,
                                                  const int* __restrict__ fl,
                                                  float* __restrict__ out,
                                                  int npick, int stage) {
    if (blockIdx.x < (unsigned)npick) {
        pick4_eh(Eh, bu, bp, bn, fl[1], out, stage, blockIdx.x * 256 + threadIdx.x);
        return;
    }
    int r = (blockIdx.x - npick) * 4 + (threadIdx.x >> 6);
    if (r >= N_NODES) return;
    const int lane = threadIdx.x & 63;
    const int g = lane >> 3;
    const int q = lane & 7;
    const int s = rowptr[r];
    const int e = rowptr[r + 1];

    __half2 acc0 = __float2half2_rn(0.f);
    __half2 acc1 = acc0, acc2 = acc0, acc3 = acc0;

    for (int base = s; base < e; base += 64) {
        int idx = base + lane;
        int2 cv = make_int2(0, 0);
        if (idx < e) cv = colcv[idx];
        int m = e - base; if (m > 64) m = 64;

        for (int j = 0; j < m; j += 8) {
            int i0 = j + g;
            bool v0 = i0 < m;
            int c0 = __shfl(cv.x, i0, 64);
            int vb = __shfl(cv.y, i0, 64);
            c0 = v0 ? c0 : 0;
            vb = v0 ? vb : 0;
            __half2 vh = *reinterpret_cast<__half2*>(&vb);
            union { float4 f; __half2 h[4]; } u;
            u.f = *reinterpret_cast<const float4*>(&Eh[c0 * EMBED + q * 8]);
            acc0 = __hfma2(vh, u.h[0], acc0);
            acc1 = __hfma2(vh, u.h[1], acc1);
            acc2 = __hfma2(vh, u.h[2], acc2);
            acc3 = __hfma2(vh, u.h[3], acc3);
        }
    }

    unsigned u0 = *reinterpret_cast<unsigned*>(&acc0);
    unsigned u1 = *reinterpret_cast<unsigned*>(&acc1);
    unsigned u2 = *reinterpret_cast<unsigned*>(&acc2);
    unsigned u3 = *reinterpret_cast<unsigned*>(&acc3);
    #pragma unroll
    for (int d = 8; d < 64; d <<= 1) {
        unsigned t0 = __shfl_xor(u0, d, 64);
        unsigned t1 = __shfl_xor(u1, d, 64);
        unsigned t2 = __shfl_xor(u2, d, 64);
        unsigned t3 = __shfl_xor(u3, d, 64);
        __half2 a0 = *reinterpret_cast<__half2*>(&u0), b0 = *reinterpret_cast<__half2*>(&t0);
        __half2 a1 = *reinterpret_cast<__half2*>(&u1), b1 = *reinterpret_cast<__half2*>(&t1);
        __half2 a2 = *reinterpret_cast<__half2*>(&u2), b2 = *reinterpret_cast<__half2*>(&t2);
        __half2 a3 = *reinterpret_cast<__half2*>(&u3), b3 = *reinterpret_cast<__half2*>(&t3);
        a0 = __hadd2(a0, b0); a1 = __hadd2(a1, b1);
        a2 = __hadd2(a2, b2); a3 = __hadd2(a3, b3);
        u0 = *reinterpret_cast<unsigned*>(&a0);
        u1 = *reinterpret_cast<unsigned*>(&a1);
        u2 = *reinterpret_cast<unsigned*>(&a2);
        u3 = *reinterpret_cast<unsigned*>(&a3);
    }
    if (g == 0) {
        uint4 o = make_uint4(u0, u1, u2, u3);
        *reinterpret_cast<uint4*>(&LEh[r * EMBED + q * 8]) = o;
    }
}

// ============ dense layer: MFMA (probe-gated) + verified VALU fallback (r22) ========
__global__ __launch_bounds__(256) void k_mlp_r26(unsigned short* __restrict__ Eh,
                                                 const unsigned short* __restrict__ LEh,
                                                 const void* __restrict__ W1,
                                                 const void* __restrict__ B1,
                                                 const void* __restrict__ W2,
                                                 const void* __restrict__ B2,
                                                 const int* __restrict__ fl, int layer) {
    __shared__ unsigned short W12s[64 * 72];
    __shared__ unsigned short W1s [64 * 72];
    __shared__ float4 XA[4][16];
    __shared__ float4 XB[4][16];
    const int fbf  = fl[0];
    const int mfok = fl[2];
    const int wofs = layer * EMBED * EMBED;
    const int bofs = layer * EMBED;
    const int t    = threadIdx.x;
    const int lane = t & 63;
    const int w    = t >> 6;

    if (mfok) {
        for (int i = t; i < 4096; i += 256) {
            int n = i >> 6, k = i & 63;
            float w1 = getf(W1, wofs + i, fbf);
            float w2 = getf(W2, wofs + i, fbf);
            W1s [n * 72 + k] = f2h(w1);
            W12s[n * 72 + k] = f2h(w1 + w2);
        }
        __syncthreads();

        const int cl = lane & 15;
        const int g  = lane >> 4;

        float bias[4];
        #pragma unroll
        for (int nt = 0; nt < 4; ++nt)
            bias[nt] = getf(B1, bofs + nt * 16 + cl, fbf) + getf(B2, bofs + nt * 16 + cl, fbf);

        half8 bw12_0[4], bw12_1[4], bw1_0[4], bw1_1[4];
        #pragma unroll
        for (int nt = 0; nt < 4; ++nt) {
            const int nrow = (nt * 16 + cl) * 72;
            bw12_0[nt] = *reinterpret_cast<const half8*>(&W12s[nrow + 0  + g * 8]);
            bw12_1[nt] = *reinterpret_cast<const half8*>(&W12s[nrow + 32 + g * 8]);
            bw1_0 [nt] = *reinterpret_cast<const half8*>(&W1s [nrow + 0  + g * 8]);
            bw1_1 [nt] = *reinterpret_cast<const half8*>(&W1s [nrow + 32 + g * 8]);
        }

        const int gw = blockIdx.x * 4 + w;
        const int nw = gridDim.x * 4;

        for (int tile = gw; tile < NTILES; tile += nw) {
            const int r0 = tile * 16;
            const unsigned short* lerow = &LEh[(r0 + cl) * EMBED];
            const unsigned short* erow  = &Eh [(r0 + cl) * EMBED];
            half8 aLE0 = *reinterpret_cast<const half8*>(&lerow[0  + g * 8]);
            half8 aLE1 = *reinterpret_cast<const half8*>(&lerow[32 + g * 8]);
            half8 aE0  = *reinterpret_cast<const half8*>(&erow [0  + g * 8]);
            half8 aE1  = *reinterpret_cast<const half8*>(&erow [32 + g * 8]);

            f32x4 acc0 = {bias[0], bias[0], bias[0], bias[0]};
            f32x4 acc1 = {bias[1], bias[1], bias[1], bias[1]};
            f32x4 acc2 = {bias[2], bias[2], bias[2], bias[2]};
            f32x4 acc3 = {bias[3], bias[3], bias[3], bias[3]};

            acc0 = __builtin_amdgcn_mfma_f32_16x16x32_f16(aLE0, bw12_0[0], acc0, 0, 0, 0);
            acc1 = __builtin_amdgcn_mfma_f32_16x16x32_f16(aLE0, bw12_0[1], acc1, 0, 0, 0);
            acc2 = __builtin_amdgcn_mfma_f32_16x16x32_f16(aLE0, bw12_0[2], acc2, 0, 0, 0);
            acc3 = __builtin_amdgcn_mfma_f32_16x16x32_f16(aLE0, bw12_0[3], acc3, 0, 0, 0);
            acc0 = __builtin_amdgcn_mfma_f32_16x16x32_f16(aLE1, bw12_1[0], acc0, 0, 0, 0);
            acc1 = __builtin_amdgcn_mfma_f32_16x16x32_f16(aLE1, bw12_1[1], acc1, 0, 0, 0);
            acc2 = __builtin_amdgcn_mfma_f32_16x16x32_f16(aLE1, bw12_1[2], acc2, 0, 0, 0);
            acc3 = __builtin_amdgcn_mfma_f32_16x16x32_f16(aLE1, bw12_1[3], acc3, 0, 0, 0);
            acc0 = __builtin_amdgcn_mfma_f32_16x16x32_f16(aE0,  bw1_0 [0], acc0, 0, 0, 0);
            acc1 = __builtin_amdgcn_mfma_f32_16x16x32_f16(aE0,  bw1_0 [1], acc1, 0, 0, 0);
            acc2 = __builtin_amdgcn_mfma_f32_16x16x32_f16(aE0,  bw1_0 [2], acc2, 0, 0, 0);
            acc3 = __builtin_amdgcn_mfma_f32_16x16x32_f16(aE0,  bw1_0 [3], acc3, 0, 0, 0);
            acc0 = __builtin_amdgcn_mfma_f32_16x16x32_f16(aE1,  bw1_1 [0], acc0, 0, 0, 0);
            acc1 = __builtin_amdgcn_mfma_f32_16x16x32_f16(aE1,  bw1_1 [1], acc1, 0, 0, 0);
            acc2 = __builtin_amdgcn_mfma_f32_16x16x32_f16(aE1,  bw1_1 [2], acc2, 0, 0, 0);
            acc3 = __builtin_amdgcn_mfma_f32_16x16x32_f16(aE1,  bw1_1 [3], acc3, 0, 0, 0);

            f32x4 h0, h1, h2, h3;
            float p0 = 0.f, p1 = 0.f, p2 = 0.f, p3 = 0.f;
            #pragma unroll
            for (int rg = 0; rg < 4; ++rg) {
                float a = acc0[rg]; float hh = (a > 0.f) ? a : 0.2f * a; h0[rg] = hh;
                float s = hh * hh;
                a = acc1[rg]; hh = (a > 0.f) ? a : 0.2f * a; h1[rg] = hh; s += hh * hh;
                a = acc2[rg]; hh = (a > 0.f) ? a : 0.2f * a; h2[rg] = hh; s += hh * hh;
                a = acc3[rg]; hh = (a > 0.f) ? a : 0.2f * a; h3[rg] = hh; s += hh * hh;
                if (rg == 0) p0 = s; else if (rg == 1) p1 = s; else if (rg == 2) p2 = s; else p3 = s;
            }
            #pragma unroll
            for (int d = 1; d < 16; d <<= 1) {
                p0 += __shfl_xor(p0, d, 64);
                p1 += __shfl_xor(p1, d, 64);
                p2 += __shfl_xor(p2, d, 64);
                p3 += __shfl_xor(p3, d, 64);
            }
            float inv0 = 1.0f / fmaxf(sqrtf(p0), 1e-12f);
            float inv1 = 1.0f / fmaxf(sqrtf(p1), 1e-12f);
            float inv2 = 1.0f / fmaxf(sqrtf(p2), 1e-12f);
            float inv3 = 1.0f / fmaxf(sqrtf(p3), 1e-12f);

            #pragma unroll
            for (int rg = 0; rg < 4; ++rg) {
                float inv = (rg == 0) ? inv0 : (rg == 1) ? inv1 : (rg == 2) ? inv2 : inv3;
                unsigned short* orow = &Eh[(r0 + g * 4 + rg) * EMBED + cl];
                orow[0]  = f2h(h0[rg] * inv);
                orow[16] = f2h(h1[rg] * inv);
                orow[32] = f2h(h2[rg] * inv);
                orow[48] = f2h(h3[rg] * inv);
            }
        }
        return;
    }

    // ---------- fallback: verified r21 VALU path ----------
    float w1r[64], w12r[64];
    if (fbf) {
        const unsigned short* p1 = (const unsigned short*)W1 + wofs + lane * 64;
        const unsigned short* p2 = (const unsigned short*)W2 + wofs + lane * 64;
        #pragma unroll
        for (int q = 0; q < 16; ++q) {
            ushort4 a = reinterpret_cast<const ushort4*>(p1)[q];
            ushort4 b = reinterpret_cast<const ushort4*>(p2)[q];
            float f0 = bf2f(a.x), f1 = bf2f(a.y), f2 = bf2f(a.z), f3 = bf2f(a.w);
            w1r[4*q+0] = f0; w1r[4*q+1] = f1; w1r[4*q+2] = f2; w1r[4*q+3] = f3;
            w12r[4*q+0] = f0 + bf2f(b.x); w12r[4*q+1] = f1 + bf2f(b.y);
            w12r[4*q+2] = f2 + bf2f(b.z); w12r[4*q+3] = f3 + bf2f(b.w);
        }
    } else {
        const float* p1 = (const float*)W1 + wofs + lane * 64;
        const float* p2 = (const float*)W2 + wofs + lane * 64;
        #pragma unroll
        for (int q = 0; q < 16; ++q) {
            float4 a = reinterpret_cast<const float4*>(p1)[q];
            float4 b = reinterpret_cast<const float4*>(p2)[q];
            w1r[4*q+0] = a.x; w1r[4*q+1] = a.y; w1r[4*q+2] = a.z; w1r[4*q+3] = a.w;
            w12r[4*q+0] = a.x + b.x; w12r[4*q+1] = a.y + b.y;
            w12r[4*q+2] = a.z + b.z; w12r[4*q+3] = a.w + b.w;
        }
    }
    const float bias = getf(B1, bofs + lane, fbf) + getf(B2, bofs + lane, fbf);

    const int gw = blockIdx.x * 4 + w;
    const int nw = gridDim.x * 4;

    int row = gw;
    float le = 0.0f, ee = 0.0f;
    if (row < N_NODES) {
        le = h2f(LEh[row * EMBED + lane]);
        ee = h2f(Eh[row * EMBED + lane]);
    }
    while (row < N_NODES) {
        const int nrow = row + nw;
        float nle = 0.0f, nee = 0.0f;
        if (nrow < N_NODES) {
            nle = h2f(LEh[nrow * EMBED + lane]);
            nee = h2f(Eh[nrow * EMBED + lane]);
        }

        ((float*)&XA[w][0])[lane] = le;
        ((float*)&XB[w][0])[lane] = ee;
        float acc0 = bias, acc1 = 0.0f;
        #pragma unroll
        for (int q = 0; q < 16; ++q) {
            float4 a = XA[w][q];
            float4 b = XB[w][q];
            acc0 = fmaf(a.x, w12r[4*q+0], acc0);
            acc1 = fmaf(b.x, w1r [4*q+0], acc1);
            acc0 = fmaf(a.y, w12r[4*q+1], acc0);
            acc1 = fmaf(b.y, w1r [4*q+1], acc1);
            acc0 = fmaf(a.z, w12r[4*q+2], acc0);
            acc1 = fmaf(b.z, w1r [4*q+2], acc1);
            acc0 = fmaf(a.w, w12r[4*q+3], acc0);
            acc1 = fmaf(b.w, w1r [4*q+3], acc1);
        }
        float acc = acc0 + acc1;
        float h = (acc > 0.0f) ? acc : 0.2f * acc;

        float s = h * h;
        #pragma unroll
        for (int d = 1; d < 64; d <<= 1) s += __shfl_xor(s, d, 64);
        const float inv = 1.0f / fmaxf(sqrtf(s), 1e-12f);

        Eh[row * EMBED + lane] = f2h(h * inv);

        row = nrow; le = nle; ee = nee;
    }
}

// -------- standalone final pick (vectorized 4-wide) --------
__global__ void k_pick_r26(const unsigned short* __restrict__ Eh, const void* __restrict__ bu,
                           const void* __restrict__ bp, const void* __restrict__ bn,
                           const int* __restrict__ fl,
                           float* __restrict__ out, int stage) {
    pick4_eh(Eh, bu, bp, bn, fl[1], out, stage, blockIdx.x * 256 + threadIdx.x);
}

// -------- launch --------
extern "C" void kernel_launch(void* const* d_in, const int* in_sizes, int n_in,
                              void* d_out, int out_size, void* d_ws, size_t ws_size,
                              hipStream_t stream) {
    const void* edge_val = d_in[0];
    const void* emb_u    = d_in[1];
    const void* emb_i    = d_in[2];
    const void* W1w      = d_in[3];
    const void* W1b      = d_in[4];
    const void* W2w      = d_in[5];
    const void* W2b      = d_in[6];
    const void* erow     = d_in[7];
    const void* ecol     = d_in[8];
    const void* bu       = d_in[9];
    const void* bp       = d_in[10];
    const void* bn       = d_in[11];

    const size_t EHB  = (size_t)N_NODES * EMBED * 2;            // 19.2 MB fp16
    const size_t RPB  = 600064;                                  // rowptr (150001 ints)
    const size_t CCB  = 4096;                                    // coarse cursors
    const size_t BBB  = 4096;                                    // bucket bases
    const size_t CVB2 = (size_t)NNZ * sizeof(int2);              // 19.2 MB final colcv
    const size_t TMPB = (size_t)NCOARSE * CAP * sizeof(int2);    // 24.1 MB bucket tmp

    const size_t need = 256 + 2 * EHB + RPB + CCB + BBB + CVB2 + TMPB;   // ~82 MB
    if (ws_size < need) return;   // zero-output signature

    char* ws = (char*)d_ws;
    int*            fl     = (int*)ws;
    unsigned short* Eh     = (unsigned short*)(ws + 256);
    unsigned short* LEh    = (unsigned short*)(ws + 256 + EHB);
    int*            rowptr = (int*)(ws + 256 + 2 * EHB);
    int*            ccur   = (int*)(ws + 256 + 2 * EHB + RPB);
    int*            bbase  = (int*)(ws + 256 + 2 * EHB + RPB + CCB);
    int2*           colcv  = (int2*)(ws + 256 + 2 * EHB + RPB + CCB + BBB);
    int2*           tmpcv  = (int2*)(ws + 256 + 2 * EHB + RPB + CCB + BBB + CVB2);
    float*          out    = (float*)d_out;

    const int GGRID = (N_NODES + 3) / 4;   // 37500 gather blocks

    k_setup_r26<<<1, 64, 0, stream>>>((const unsigned short*)edge_val, erow, fl, ccur);

    // init + pick stage-0 (from raw inputs) fused
    k_init_r26<<<PICKB + (N_NODES * EMBED + 255) / 256, 256, 0, stream>>>(
        emb_u, emb_i, fl, Eh, bu, bp, bn, out);

    k_partA_r26<<<(NNZ + TILE - 1) / TILE, 256, 0, stream>>>(edge_val, erow, ecol, fl,
                                                             ccur, tmpcv);
    k_bscan_r26<<<1, 64, 0, stream>>>(ccur, bbase, rowptr);
    k_place2_r26<<<NCOARSE, 256, 0, stream>>>(ccur, bbase, tmpcv, colcv, rowptr);

    for (int l = 0; l < 3; ++l) {
        const int npick = (l == 0) ? 0 : PICKB;       // fold pick(stage=l) into gath(l)
        k_gath_r26<<<GGRID + npick, 256, 0, stream>>>(rowptr, colcv, Eh, LEh,
                                                      bu, bp, bn, fl, out, npick, l);
        k_mlp_r26<<<768, 256, 0, stream>>>(Eh, LEh, W1w, W1b, W2w, W2b, fl, l);
    }
    k_pick_r26<<<PICKB, 256, 0, stream>>>(Eh, bu, bp, bn, fl, out, 3);
}